// Round 2
// baseline (974.329 us; speedup 1.0000x reference)
//
#include <hip/hip_runtime.h>

typedef unsigned short u16;
typedef unsigned int   u32;

#define D_MODEL 1024
#define D_INNER 2048
#define D_STATE 16
#define SEQLEN  2048
#define BATCH   4
#define NROWS   (BATCH*SEQLEN)   // 8192
#define CHUNK   128
#define NCHUNK  (SEQLEN/CHUNK)   // 16

__device__ __forceinline__ float b2f(u16 v){
  union { u32 i; float f; } u; u.i = ((u32)v) << 16; return u.f;
}
__device__ __forceinline__ u16 f2b(float f){
  union { float f; u32 i; } u; u.f = f;
  u32 x = u.i;
  return (u16)((x + 0x7fffu + ((x >> 16) & 1u)) >> 16);  // RNE
}
__device__ __forceinline__ float h2f(u16 v){
  _Float16 h; __builtin_memcpy(&h, &v, 2); return (float)h;
}
__device__ __forceinline__ u16 f2h(float f){
  _Float16 h = (_Float16)f; u16 v; __builtin_memcpy(&v, &h, 2); return v;
}

typedef __bf16 bf16x8 __attribute__((ext_vector_type(8)));
typedef float  f32x4  __attribute__((ext_vector_type(4)));

// async global->LDS, 16B per lane; data for lane i lands at lds + i*16B.
__device__ __forceinline__ void async16(u16* lds, const u16* g){
  __builtin_amdgcn_global_load_lds(
      (const __attribute__((address_space(1))) void*)g,
      (__attribute__((address_space(3))) void*)lds,
      16, 0, 0);
}

// ---------------------------------------------------------------------------
// fp32 [Kd][Nd] -> bf16 transposed [Nd][Kd]   (32x32 LDS tiles)
// ---------------------------------------------------------------------------
__global__ __launch_bounds__(256) void wcvt_t_kernel(
    const float* __restrict__ W, u16* __restrict__ Bt, int Kd, int Nd)
{
  __shared__ u16 tile[32][33];
  const int n0 = blockIdx.x*32, k0 = blockIdx.y*32;
  const int tx = threadIdx.x & 31, ty = threadIdx.x >> 5;  // ty 0..7
  #pragma unroll
  for (int i=0;i<32;i+=8)
    tile[ty+i][tx] = f2b(W[(size_t)(k0+ty+i)*Nd + n0+tx]);   // tile[k][n]
  __syncthreads();
  #pragma unroll
  for (int i=0;i<32;i+=8)
    Bt[(size_t)(n0+ty+i)*Kd + k0+tx] = tile[tx][ty+i];
}

// Wx [2048][32] cols 16..31 -> Wxt bf16 [16][2048]
__global__ __launch_bounds__(256) void wxcvt_kernel(
    const float* __restrict__ Wx, u16* __restrict__ Wxt)
{
  const int k = blockIdx.x*256 + threadIdx.x;   // 0..2047
  #pragma unroll
  for (int n=0;n<16;n++)
    Wxt[n*D_INNER + k] = f2b(Wx[(size_t)k*32 + 16 + n]);
}

// ---------------------------------------------------------------------------
// Fused LayerNorm: x[row][1024] fp32 -> xn bf16
// ---------------------------------------------------------------------------
__global__ __launch_bounds__(256) void ln_kernel(
    const float* __restrict__ x, const float* __restrict__ g,
    const float* __restrict__ be, u16* __restrict__ xn)
{
  const int row = blockIdx.x;
  const float* xr = x + (size_t)row * D_MODEL;
  const int tid = threadIdx.x;
  float v[4]; float s = 0.f, s2 = 0.f;
  #pragma unroll
  for (int j=0;j<4;j++){
    float f = xr[tid + 256*j];
    v[j] = f; s += f; s2 += f*f;
  }
  #pragma unroll
  for (int o=32;o>0;o>>=1){ s += __shfl_down(s,o); s2 += __shfl_down(s2,o); }
  __shared__ float sh[8];
  const int wave = tid>>6, lane = tid&63;
  if (lane==0){ sh[wave]=s; sh[4+wave]=s2; }
  __syncthreads();
  const float ts  = sh[0]+sh[1]+sh[2]+sh[3];
  const float ts2 = sh[4]+sh[5]+sh[6]+sh[7];
  const float mu  = ts * (1.f/D_MODEL);
  const float var = ts2 * (1.f/D_MODEL) - mu*mu;
  const float rstd = rsqrtf(var + 1e-5f);
  u16* xo = xn + (size_t)row * D_MODEL;
  #pragma unroll
  for (int j=0;j<4;j++){
    int i = tid + 256*j;
    xo[i] = f2b((v[j]-mu)*rstd * g[i] + be[i]);
  }
}

// ---------------------------------------------------------------------------
// m201-style MFMA GEMM. BN=256 fixed; BM = MF*32 (MF=8 -> 256x256, MF=4 ->
// 128x256). BK=64 stored as two ks-subtiles [BM][32] per double-buffer.
// 8 waves (2M x 4N); per-wave tile MF*16 x 64; MF/2 phases per K-tile, each:
//   { 4-8 ds_read_b128 ; stage 2-3 chunks of tile kt+1 ; counted vmcnt ;
//     s_barrier ; lgkmcnt(0) ; setprio(1) ; 16 independent MFMA ; setprio(0) ;
//     s_barrier }
// Counted-vmcnt pipeline (T4): in-flight window stays 3..8 loads, never 0 in
// the main loop: MF=8: vmcnt(2) after p0, vmcnt(4) after p3; MF=4: vmcnt(3)
// after each of the 2 phases. Swizzle: 16B granule XOR (verified 0-conflict
// in this kernel's lineage), applied on pre-swizzled GLOBAL source (staging)
// and swizzled ds_read address (read) -- linear global_load_lds dest.
// A [M][K] bf16 ; Bt [N][K] bf16 (pre-transposed).
// EPI 0: bf16 ; EPI 1: softplus(v+bias)->fp16 ; EPI 2: v+resid->fp32
// ---------------------------------------------------------------------------
template<int EPI, int MF>
__global__ __launch_bounds__(512, 2) void gemm256(
    const u16* __restrict__ A, const u16* __restrict__ Bt,
    const float* __restrict__ bias, const float* __restrict__ resid,
    void* __restrict__ outv, int M, int N, int K, int gx, int gy)
{
  constexpr int BM     = MF*32;            // 256 or 128
  constexpr int AKS_E  = BM*32;            // elems per A ks-subtile
  constexpr int ABUF_E = 2*AKS_E;          // elems per A buffer
  constexpr int ABUF_B = ABUF_E*2;         // bytes per A buffer
  constexpr int AKS_B  = AKS_E*2;          // bytes per A ks-subtile
  constexpr int CH     = (MF==8) ? 8 : 6;  // staging chunks per K-tile
  constexpr int STG    = CH/(MF/2);        // chunks staged per phase (2 or 3)

  __shared__ __align__(16) u16 As[2*ABUF_E];     // 64 KB or 32 KB
  __shared__ __align__(16) u16 Bs[2*2*8192];     // 64 KB  (2 buf x 2 ks x [256][32])

  const int tid  = threadIdx.x;
  const int wave = tid >> 6, lane = tid & 63;
  const int quad = lane >> 4, l16 = lane & 15;
  const int wm = wave >> 2, wn = wave & 3;   // 2 x 4 wave grid

  // XCD-aware swizzle (needs gx % 8 == 0); fallback: n-column major.
  const int lid = blockIdx.x;
  int bx, by;
  if ((gx & 7) == 0) {
    const int xcd = lid & 7, q = lid >> 3;
    const int cpx = gx >> 3;
    const int qd  = q / gy;
    bx = xcd*cpx + qd;
    by = q - qd*gy;
  } else {
    bx = lid / gy;
    by = lid - bx*gy;
  }
  const int m0 = by*BM, n0 = bx*256;

  // ---- staging: per-thread global src (pre-swizzled granule), uniform dest ----
  const int gl   = (tid & 3) ^ ((tid >> 3) & 3);   // logical granule at phys slot tid&3
  const int srow = tid >> 2;                       // 0..127
  const u16* pA = A  + (size_t)(m0 + srow)*K + gl*8;
  const u16* pB = Bt + (size_t)(n0 + srow)*K + gl*8;

  // chunk id -> one async16.  MF=8: [A(s0,r0),A(s0,r1),B(s0,r0),B(s0,r1),
  // A(s1,r0),A(s1,r1),B(s1,r0),B(s1,r1)]   MF=4: [A(s0),B(s0,r0),B(s0,r1),
  // A(s1),B(s1,r0),B(s1,r1)]   (ks0 group first = consumption order)
  auto STAGE = [&](int id, int kt2, int c2){
    const size_t ko = (size_t)kt2*64;
    if constexpr (MF == 8) {
      const int s = id >> 2, rh = id & 1;
      if ((id & 2) == 0)
        async16(As + (c2*2+s)*AKS_E + rh*4096 + wave*512,
                pA + (size_t)rh*128*K + ko + s*32);
      else
        async16(Bs + (c2*2+s)*8192 + rh*4096 + wave*512,
                pB + (size_t)rh*128*K + ko + s*32);
    } else {
      const int s = id/3, r = id - s*3;
      if (r == 0)
        async16(As + (c2*2+s)*AKS_E + wave*512, pA + ko + s*32);
      else
        async16(Bs + (c2*2+s)*8192 + (r-1)*4096 + wave*512,
                pB + (size_t)(r-1)*128*K + ko + s*32);
    }
  };

  // ---- fragment read bases (swizzled read side, byte offsets) ----
  const int swz = quad ^ ((l16 >> 1) & 3);
  const char* aB = (const char*)As + (wm*(MF*16) + l16)*64 + swz*16;
  const char* bB = (const char*)Bs + (wn*64      + l16)*64 + swz*16;

  f32x4 acc[MF][4];
  #pragma unroll
  for (int i=0;i<MF;i++)
    #pragma unroll
    for (int j=0;j<4;j++) acc[i][j] = (f32x4){0.f,0.f,0.f,0.f};

  const int KT = K >> 6;          // BK=64 tiles (KT >= 2 for all our shapes)

  // ---- prologue: stage tile 0; wait for its ks0 group; publish ----
  #pragma unroll
  for (int id=0; id<CH; ++id) STAGE(id, 0, 0);
  if constexpr (MF==8) asm volatile("s_waitcnt vmcnt(4)" ::: "memory");
  else                 asm volatile("s_waitcnt vmcnt(3)" ::: "memory");
  __builtin_amdgcn_s_barrier();
  __builtin_amdgcn_sched_barrier(0);

  bf16x8 bfr[2][4];               // B fragments for ks0/ks1, live across phases

  for (int kt = 0; kt < KT; ++kt){
    const int c   = kt & 1;
    const int kt2 = (kt+1 < KT) ? kt+1 : KT-1;   // clamp keeps vmcnt uniform
    const int c2  = (kt+1) & 1;                  // dead-parity buffer at tail
    const char* aT = aB + c*ABUF_B;
    const char* bT = bB + c*32768;

    #pragma unroll
    for (int p = 0; p < MF/2; ++p){
      const int ks = p & 1;
      const int mg = (p >> 1) * 4;

      // ds-read this phase's fragments
      bf16x8 af[4];
      #pragma unroll
      for (int i=0;i<4;i++)
        af[i] = *(const bf16x8*)(aT + ks*AKS_B + (mg+i)*1024);
      if (p < 2) {
        #pragma unroll
        for (int nf=0;nf<4;nf++)
          bfr[ks][nf] = *(const bf16x8*)(bT + ks*16384 + nf*1024);
      }

      // stage next tile's chunks, evenly
      #pragma unroll
      for (int i=0;i<STG;i++) STAGE(p*STG+i, kt2, c2);

      // counted waits: prev tile's ks1 must land before p1; next tile's ks0
      // before its p0.  Window stays 3..8 loads in flight, never drained.
      if (p == 0) {
        if constexpr (MF==8) asm volatile("s_waitcnt vmcnt(2)" ::: "memory");
        else                 asm volatile("s_waitcnt vmcnt(3)" ::: "memory");
      }
      if (p == MF/2 - 1) {
        if constexpr (MF==8) asm volatile("s_waitcnt vmcnt(4)" ::: "memory");
        else                 asm volatile("s_waitcnt vmcnt(3)" ::: "memory");
      }
      __builtin_amdgcn_s_barrier();
      asm volatile("s_waitcnt lgkmcnt(0)" ::: "memory");
      __builtin_amdgcn_sched_barrier(0);
      __builtin_amdgcn_s_setprio(1);
      #pragma unroll
      for (int mf=0;mf<4;mf++)
        #pragma unroll
        for (int nf=0;nf<4;nf++)
          acc[mg+mf][nf] = __builtin_amdgcn_mfma_f32_16x16x32_bf16(
              af[mf], bfr[ks][nf], acc[mg+mf][nf], 0, 0, 0);
      __builtin_amdgcn_s_setprio(0);
      __builtin_amdgcn_s_barrier();
    }
  }
  asm volatile("s_waitcnt vmcnt(0)" ::: "memory");   // drain tail staging

  // ---- epilogue ----
  #pragma unroll
  for (int mf=0; mf<MF; mf++){
    #pragma unroll
    for (int nf=0; nf<4; nf++){
      const int col = n0 + wn*64 + nf*16 + l16;
      #pragma unroll
      for (int j=0;j<4;j++){
        const int row = m0 + wm*(MF*16) + mf*16 + quad*4 + j;
        float v = acc[mf][nf][j];
        if (EPI == 1) {
          v += bias[col];
          v = (v > 20.f) ? v : log1pf(__expf(v));
          ((u16*)outv)[(size_t)row*N + col] = f2h(v);       // delta fp16
        } else if (EPI == 2) {
          v += resid[(size_t)row*N + col];
          ((float*)outv)[(size_t)row*N + col] = v;          // final out fp32
        } else {
          ((u16*)outv)[(size_t)row*N + col] = f2b(v);       // bf16 activation
        }
      }
    }
  }
}

// ---------------------------------------------------------------------------
// Causal depthwise conv(width 4) + bias + SiLU, 8 channels/thread vectorized.
// ---------------------------------------------------------------------------
__global__ __launch_bounds__(256) void conv_silu_kernel(
    const u16* __restrict__ xz, const float* __restrict__ cw,
    const float* __restrict__ cb, u16* __restrict__ u)
{
  const int idx = blockIdx.x*256 + threadIdx.x;   // (bt, c-group)
  const int c0 = (idx & 255) * 8;
  const int bt = idx >> 8;
  const int t  = bt & (SEQLEN-1);
  float acc[8];
  #pragma unroll
  for (int j=0;j<8;j++) acc[j] = cb[c0+j];
  #pragma unroll
  for (int k=0;k<4;k++){
    if (t - 3 + k >= 0){
      bf16x8 xv = *reinterpret_cast<const bf16x8*>(xz + (size_t)(bt-3+k)*4096 + c0);
      #pragma unroll
      for (int j=0;j<8;j++)
        acc[j] = fmaf(cw[(c0+j)*4 + k], (float)xv[j], acc[j]);
    }
  }
  u16 o[8];
  #pragma unroll
  for (int j=0;j<8;j++){
    float sv = acc[j] / (1.f + __expf(-acc[j]));
    o[j] = f2b(sv);
  }
  __builtin_memcpy(u + (size_t)bt*D_INNER + c0, o, 16);
}

// ---------------------------------------------------------------------------
// x_proj (cols 16..31 only): one wave per row, lane=(kq,n), bf16x8 both streams.
// ---------------------------------------------------------------------------
__global__ __launch_bounds__(256) void xproj_kernel(
    const u16* __restrict__ u, const u16* __restrict__ Wxt, float* __restrict__ Bm)
{
  const int wave = threadIdx.x >> 6, lane = threadIdx.x & 63;
  const int m = blockIdx.x*4 + wave;
  const int n = lane & 15, kq = lane >> 4;
  const u16* ur = u   + (size_t)m*D_INNER + kq*512;
  const u16* wr = Wxt + (size_t)n*D_INNER + kq*512;
  float acc = 0.f;
  #pragma unroll 4
  for (int i=0;i<512;i+=8){
    bf16x8 uv = *reinterpret_cast<const bf16x8*>(ur + i);
    bf16x8 wv = *reinterpret_cast<const bf16x8*>(wr + i);
    #pragma unroll
    for (int j=0;j<8;j++) acc = fmaf((float)uv[j], (float)wv[j], acc);
  }
  acc += __shfl_xor(acc, 16);
  acc += __shfl_xor(acc, 32);
  if (lane < 16) Bm[(size_t)m*16 + n] = acc;
}

// ---------------------------------------------------------------------------
// Chunked selective scan, 3 passes (exact linear-recurrence decomposition).
// ---------------------------------------------------------------------------
__global__ __launch_bounds__(256) void scan_partial(
    const u16* __restrict__ uu, const u16* __restrict__ delta16,
    const float* __restrict__ Bm, const float* __restrict__ Alog,
    float* __restrict__ hend, float* __restrict__ sumdt)
{
  const int b = blockIdx.y, ch = blockIdx.z;
  const int c = blockIdx.x*256 + threadIdx.x;
  const int row0 = b*SEQLEN + ch*CHUNK;
  float A[16], h[16];
  #pragma unroll
  for (int s=0;s<16;s++){ A[s] = -__expf(Alog[c*16+s]); h[s]=0.f; }
  __shared__ float Bsh[CHUNK*16];
  const float* src = Bm + (size_t)row0*16;
  #pragma unroll
  for (int j=0;j<8;j++) Bsh[threadIdx.x + 256*j] = src[threadIdx.x + 256*j];
  __syncthreads();

  float S = 0.f;
  float dta[8], uva[8], dtb[8], uvb[8];
  #pragma unroll
  for (int j=0;j<8;j++){
    size_t r = (size_t)(row0+j);
    dta[j] = h2f(delta16[r*D_INNER+c]);
    uva[j] = b2f(uu[r*D_INNER+c]);
  }
  #pragma unroll 1
  for (int g=0; g<CHUNK; g+=16){
    #pragma unroll
    for (int j=0;j<8;j++){
      int tl = g+8+j; tl = tl < CHUNK ? tl : CHUNK-1;
      size_t r = (size_t)(row0+tl);
      dtb[j] = h2f(delta16[r*D_INNER+c]);
      uvb[j] = b2f(uu[r*D_INNER+c]);
    }
    #pragma unroll
    for (int j=0;j<8;j++){
      float dt=dta[j], uv=uva[j]; S += dt; float xv=dt*uv;
      const float* Bt = &Bsh[(g+j)*16];
      #pragma unroll
      for (int s=0;s<16;s++) h[s] = fmaf(h[s], __expf(dt*A[s]), xv*Bt[s]);
    }
    #pragma unroll
    for (int j=0;j<8;j++){
      int tl = g+16+j; tl = tl < CHUNK ? tl : CHUNK-1;
      size_t r = (size_t)(row0+tl);
      dta[j] = h2f(delta16[r*D_INNER+c]);
      uva[j] = b2f(uu[r*D_INNER+c]);
    }
    #pragma unroll
    for (int j=0;j<8;j++){
      float dt=dtb[j], uv=uvb[j]; S += dt; float xv=dt*uv;
      const float* Bt = &Bsh[(g+8+j)*16];
      #pragma unroll
      for (int s=0;s<16;s++) h[s] = fmaf(h[s], __expf(dt*A[s]), xv*Bt[s]);
    }
  }
  const size_t base = ((size_t)(b*NCHUNK+ch)*16)*D_INNER + c;
  #pragma unroll
  for (int s=0;s<16;s++) hend[base + (size_t)s*D_INNER] = h[s];
  sumdt[(size_t)(b*NCHUNK+ch)*D_INNER + c] = S;
}

__global__ __launch_bounds__(256) void scan_combine(
    const float* __restrict__ hend, const float* __restrict__ sumdt,
    const float* __restrict__ Alog, float* __restrict__ hin)
{
  const int b = blockIdx.y;
  const int c = blockIdx.x*256 + threadIdx.x;
  float A[16], h[16];
  #pragma unroll
  for (int s=0;s<16;s++){ A[s] = -__expf(Alog[c*16+s]); h[s]=0.f; }
  #pragma unroll 1
  for (int k=0;k<NCHUNK;k++){
    const size_t base = ((size_t)(b*NCHUNK+k)*16)*D_INNER + c;
    #pragma unroll
    for (int s=0;s<16;s++) hin[base + (size_t)s*D_INNER] = h[s];
    const float S = sumdt[(size_t)(b*NCHUNK+k)*D_INNER + c];
    #pragma unroll
    for (int s=0;s<16;s++)
      h[s] = fmaf(h[s], __expf(S*A[s]), hend[base + (size_t)s*D_INNER]);
  }
}

__global__ __launch_bounds__(256) void scan_final(
    const u16* __restrict__ uu, const u16* __restrict__ delta16,
    const float* __restrict__ Bm, const u16* __restrict__ xz,
    const float* __restrict__ Alog, const float* __restrict__ Dpar,
    const float* __restrict__ hin, u16* __restrict__ yg)
{
  const int b = blockIdx.y, ch = blockIdx.z;
  const int c = blockIdx.x*256 + threadIdx.x;
  const int row0 = b*SEQLEN + ch*CHUNK;
  float A[16], h[16];
  const size_t base = ((size_t)(b*NCHUNK+ch)*16)*D_INNER + c;
  #pragma unroll
  for (int s=0;s<16;s++){
    A[s] = -__expf(Alog[c*16+s]);
    h[s] = hin[base + (size_t)s*D_INNER];
  }
  const float Dc = Dpar[c];
  __shared__ float Bsh[CHUNK*16];
  const float* src = Bm + (size_t)row0*16;
  #pragma unroll
  for (int j=0;j<8;j++) Bsh[threadIdx.x + 256*j] = src[threadIdx.x + 256*j];
  __syncthreads();

  float dta[8], uva[8], zva[8], dtb[8], uvb[8], zvb[8];
  #pragma unroll
  for (int j=0;j<8;j++){
    size_t r = (size_t)(row0+j);
    dta[j] = h2f(delta16[r*D_INNER+c]);
    uva[j] = b2f(uu[r*D_INNER+c]);
    zva[j] = b2f(xz[r*4096 + D_INNER + c]);
  }
  #pragma unroll 1
  for (int g=0; g<CHUNK; g+=16){
    #pragma unroll
    for (int j=0;j<8;j++){
      int tl = g+8+j; tl = tl < CHUNK ? tl : CHUNK-1;
      size_t r = (size_t)(row0+tl);
      dtb[j] = h2f(delta16[r*D_INNER+c]);
      uvb[j] = b2f(uu[r*D_INNER+c]);
      zvb[j] = b2f(xz[r*4096 + D_INNER + c]);
    }
    #pragma unroll
    for (int j=0;j<8;j++){
      float dt=dta[j], uv=uva[j], zv=zva[j];
      float xv=dt*uv, y=0.f;
      const float* Bt = &Bsh[(g+j)*16];
      #pragma unroll
      for (int s=0;s<16;s++){
        h[s] = fmaf(h[s], __expf(dt*A[s]), xv*Bt[s]);
        y += h[s];
      }
      y = fmaf(uv, Dc, y);
      float gz = zv/(1.f+__expf(-zv));
      yg[(size_t)(row0+g+j)*D_INNER + c] = f2b(y*gz);
    }
    #pragma unroll
    for (int j=0;j<8;j++){
      int tl = g+16+j; tl = tl < CHUNK ? tl : CHUNK-1;
      size_t r = (size_t)(row0+tl);
      dta[j] = h2f(delta16[r*D_INNER+c]);
      uva[j] = b2f(uu[r*D_INNER+c]);
      zva[j] = b2f(xz[r*4096 + D_INNER + c]);
    }
    #pragma unroll
    for (int j=0;j<8;j++){
      float dt=dtb[j], uv=uvb[j], zv=zvb[j];
      float xv=dt*uv, y=0.f;
      const float* Bt = &Bsh[(g+8+j)*16];
      #pragma unroll
      for (int s=0;s<16;s++){
        h[s] = fmaf(h[s], __expf(dt*A[s]), xv*Bt[s]);
        y += h[s];
      }
      y = fmaf(uv, Dc, y);
      float gz = zv/(1.f+__expf(-zv));
      yg[(size_t)(row0+g+8+j)*D_INNER + c] = f2b(y*gz);
    }
  }
}

// ---------------------------------------------------------------------------
extern "C" void kernel_launch(void* const* d_in, const int* in_sizes, int n_in,
                              void* d_out, int out_size, void* d_ws, size_t ws_size,
                              hipStream_t stream)
{
  const float* x    = (const float*)d_in[0];
  const float* lng  = (const float*)d_in[1];
  const float* lnb  = (const float*)d_in[2];
  const float* W1   = (const float*)d_in[3];
  const float* cw   = (const float*)d_in[4];
  const float* cb   = (const float*)d_in[5];
  const float* Wx   = (const float*)d_in[6];
  const float* Wdt  = (const float*)d_in[7];
  const float* dtb  = (const float*)d_in[8];
  const float* Alog = (const float*)d_in[9];
  const float* Dpar = (const float*)d_in[10];
  const float* Wout = (const float*)d_in[11];

  // workspace layout (MiB offsets), total ~199 MiB
  char* ws = (char*)d_ws;
  u16*   dlt   = (u16*)(ws);
  u16*   xn    = (u16*)(ws);                 // alias (sequenced)
  u16*   xz    = (u16*)(ws + (32llu<<20));
  u16*   uu    = (u16*)(ws + (96llu<<20));
  float* Bm    = (float*)(ws + (128llu<<20));
  u16*   W1t   = (u16*)(ws + (129llu<<20));
  u16*   Wdtt  = (u16*)(ws + (137llu<<20));
  u16*   Woutt = (u16*)(ws + (145llu<<20));
  u16*   yg    = (u16*)(ws + (149llu<<20));
  float* hend  = (float*)(ws + (181llu<<20));
  float* sumdt = (float*)(ws + (189llu<<20));
  float* hin   = (float*)(ws + (190llu<<20));
  u16*   Wxt   = (u16*)(ws + (198llu<<20));

  // weights -> bf16, transposed to [N][K]
  wcvt_t_kernel<<<dim3(2*D_INNER/32, D_MODEL/32), 256, 0, stream>>>(W1,  W1t,  D_MODEL, 2*D_INNER);
  wcvt_t_kernel<<<dim3(D_INNER/32,  D_INNER/32), 256, 0, stream>>>(Wdt, Wdtt, D_INNER, D_INNER);
  wcvt_t_kernel<<<dim3(D_MODEL/32,  D_INNER/32), 256, 0, stream>>>(Wout,Woutt,D_INNER, D_MODEL);
  wxcvt_kernel<<<D_INNER/256, 256, 0, stream>>>(Wx, Wxt);

  ln_kernel<<<NROWS, 256, 0, stream>>>(x, lng, lnb, xn);

  {
    const int gx = 2*D_INNER/256, gy = NROWS/256;   // 16 x 32
    gemm256<0,8><<<gx*gy, 512, 0, stream>>>(
        xn, W1t, nullptr, nullptr, (void*)xz, NROWS, 2*D_INNER, D_MODEL, gx, gy);
  }

  conv_silu_kernel<<<(NROWS*D_INNER/8)/256, 256, 0, stream>>>(xz, cw, cb, uu);

  xproj_kernel<<<NROWS/4, 256, 0, stream>>>(uu, Wxt, Bm);

  {
    const int gx = D_INNER/256, gy = NROWS/256;     // 8 x 32
    gemm256<1,8><<<gx*gy, 512, 0, stream>>>(
        uu, Wdtt, dtb, nullptr, (void*)dlt, NROWS, D_INNER, D_INNER, gx, gy);
  }

  scan_partial<<<dim3(D_INNER/256, BATCH, NCHUNK), 256, 0, stream>>>(
      uu, dlt, Bm, Alog, hend, sumdt);
  scan_combine<<<dim3(D_INNER/256, BATCH), 256, 0, stream>>>(
      hend, sumdt, Alog, hin);
  scan_final<<<dim3(D_INNER/256, BATCH, NCHUNK), 256, 0, stream>>>(
      uu, dlt, Bm, xz, Alog, Dpar, hin, yg);

  {
    const int gx = D_MODEL/256, gy = NROWS/128;     // 4 x 64 = 256 blocks (BM=128)
    gemm256<2,4><<<gx*gy, 512, 0, stream>>>(
        yg, Woutt, nullptr, x, d_out, NROWS, D_MODEL, D_INNER, gx, gy);
  }

  (void)in_sizes; (void)n_in; (void)out_size; (void)ws_size;
}

// Round 3
// 882.875 us; speedup vs baseline: 1.1036x; 1.1036x over previous
//
#include <hip/hip_runtime.h>

typedef unsigned short u16;
typedef unsigned int   u32;

#define D_MODEL 1024
#define D_INNER 2048
#define D_STATE 16
#define SEQLEN  2048
#define BATCH   4
#define NROWS   (BATCH*SEQLEN)   // 8192
#define CHUNK   128
#define NCHUNK  (SEQLEN/CHUNK)   // 16

__device__ __forceinline__ float b2f(u16 v){
  union { u32 i; float f; } u; u.i = ((u32)v) << 16; return u.f;
}
__device__ __forceinline__ u16 f2b(float f){
  union { float f; u32 i; } u; u.f = f;
  u32 x = u.i;
  return (u16)((x + 0x7fffu + ((x >> 16) & 1u)) >> 16);  // RNE
}
__device__ __forceinline__ float h2f(u16 v){
  _Float16 h; __builtin_memcpy(&h, &v, 2); return (float)h;
}
__device__ __forceinline__ u16 f2h(float f){
  _Float16 h = (_Float16)f; u16 v; __builtin_memcpy(&v, &h, 2); return v;
}

typedef __bf16 bf16x8 __attribute__((ext_vector_type(8)));
typedef float  f32x4  __attribute__((ext_vector_type(4)));

// async global->LDS, 16B per lane; data for lane i lands at lds + i*16B.
__device__ __forceinline__ void async16(u16* lds, const u16* g){
  __builtin_amdgcn_global_load_lds(
      (const __attribute__((address_space(1))) void*)g,
      (__attribute__((address_space(3))) void*)lds,
      16, 0, 0);
}

// ---------------------------------------------------------------------------
// fp32 [Kd][Nd] -> bf16 transposed [Nd][Kd]   (32x32 LDS tiles)
// ---------------------------------------------------------------------------
__global__ __launch_bounds__(256) void wcvt_t_kernel(
    const float* __restrict__ W, u16* __restrict__ Bt, int Kd, int Nd)
{
  __shared__ u16 tile[32][33];
  const int n0 = blockIdx.x*32, k0 = blockIdx.y*32;
  const int tx = threadIdx.x & 31, ty = threadIdx.x >> 5;  // ty 0..7
  #pragma unroll
  for (int i=0;i<32;i+=8)
    tile[ty+i][tx] = f2b(W[(size_t)(k0+ty+i)*Nd + n0+tx]);   // tile[k][n]
  __syncthreads();
  #pragma unroll
  for (int i=0;i<32;i+=8)
    Bt[(size_t)(n0+ty+i)*Kd + k0+tx] = tile[tx][ty+i];
}

// Wx [2048][32] cols 16..31 -> Wxt bf16 [16][2048]
__global__ __launch_bounds__(256) void wxcvt_kernel(
    const float* __restrict__ Wx, u16* __restrict__ Wxt)
{
  const int k = blockIdx.x*256 + threadIdx.x;   // 0..2047
  #pragma unroll
  for (int n=0;n<16;n++)
    Wxt[n*D_INNER + k] = f2b(Wx[(size_t)k*32 + 16 + n]);
}

// ---------------------------------------------------------------------------
// Fused LayerNorm: x[row][1024] fp32 -> xn bf16
// ---------------------------------------------------------------------------
__global__ __launch_bounds__(256) void ln_kernel(
    const float* __restrict__ x, const float* __restrict__ g,
    const float* __restrict__ be, u16* __restrict__ xn)
{
  const int row = blockIdx.x;
  const float* xr = x + (size_t)row * D_MODEL;
  const int tid = threadIdx.x;
  float v[4]; float s = 0.f, s2 = 0.f;
  #pragma unroll
  for (int j=0;j<4;j++){
    float f = xr[tid + 256*j];
    v[j] = f; s += f; s2 += f*f;
  }
  #pragma unroll
  for (int o=32;o>0;o>>=1){ s += __shfl_down(s,o); s2 += __shfl_down(s2,o); }
  __shared__ float sh[8];
  const int wave = tid>>6, lane = tid&63;
  if (lane==0){ sh[wave]=s; sh[4+wave]=s2; }
  __syncthreads();
  const float ts  = sh[0]+sh[1]+sh[2]+sh[3];
  const float ts2 = sh[4]+sh[5]+sh[6]+sh[7];
  const float mu  = ts * (1.f/D_MODEL);
  const float var = ts2 * (1.f/D_MODEL) - mu*mu;
  const float rstd = rsqrtf(var + 1e-5f);
  u16* xo = xn + (size_t)row * D_MODEL;
  #pragma unroll
  for (int j=0;j<4;j++){
    int i = tid + 256*j;
    xo[i] = f2b((v[j]-mu)*rstd * g[i] + be[i]);
  }
}

// ---------------------------------------------------------------------------
// 128x64 MFMA GEMM, BK=64, small-block high-occupancy variant.
// 4 waves (2M x 2N), wave tile 64x32, acc[4][2] (32 AGPR) -> ~5 blocks/CU
// (24 KB LDS, low regs). Simple verified 2-barrier loop; latency hiding
// comes from block-level TLP (5 independent blocks per CU phase-shifted),
// per m114/m97 evidence, instead of intra-block pipelining.
// Swizzle: 16B-granule XOR (verified 0-conflict lineage): store places
// logical granule g at phys p = g ^ ((row>>1)&3) via pre-swizzled global
// source (linear global_load_lds dest); read picks phys = quad^((l16>>1)&3).
// A [M][K] bf16 ; Bt [N][K] bf16 (pre-transposed).
// EPI 0: bf16 ; EPI 1: softplus(v+bias)->fp16 ; EPI 2: v+resid->fp32
// ---------------------------------------------------------------------------
template<int EPI>
__global__ __launch_bounds__(256) void gemm_bn64(
    const u16* __restrict__ A, const u16* __restrict__ Bt,
    const float* __restrict__ bias, const float* __restrict__ resid,
    void* __restrict__ outv, int M, int N, int K, int gx, int gy)
{
  __shared__ __align__(16) u16 As[2*128*32];   // 16 KB: ks0, ks1
  __shared__ __align__(16) u16 Bs[2*64*32];    //  8 KB
  const int tid  = threadIdx.x;
  const int wave = tid >> 6, lane = tid & 63;
  const int quad = lane >> 4, l16 = lane & 15;
  const int wm = wave >> 1, wn = wave & 1;     // 2 x 2 wave grid

  // XCD swizzle: consecutive blocks on one XCD share the same n-column.
  const int lid = blockIdx.x;
  const int xcd = lid & 7, q = lid >> 3;
  const int cpx = gx >> 3;
  const int qd  = q / gy;
  const int bx  = xcd*cpx + qd;
  const int by  = q - qd*gy;
  const int m0 = by*128, n0 = bx*64;

  // ---- staging: pre-swizzled global source, linear LDS dest ----
  const int gl   = (lane & 3) ^ ((lane >> 3) & 3);  // logical granule at phys lane&3
  const int lrow = lane >> 2;                       // 0..15 row within chunk
  const u16* pa = A  + (size_t)(m0 + lrow)*K + gl*8;
  const u16* pb = Bt + (size_t)(n0 + lrow)*K + gl*8;
  // per-wave chunk dests (16 rows x 32 k = 1 KB each)
  u16* dA0 = As + wave*512;        // A rows 16w..16w+15
  u16* dA1 = As + (wave+4)*512;    // A rows 16(w+4)..
  u16* dB0 = Bs + wave*512;        // B rows 16w..

  // ---- fragment read bases (swizzled read side, byte offsets) ----
  const int sw = quad ^ ((l16 >> 1) & 3);
  const char* aB = (const char*)As + (wm*64 + l16)*64 + sw*16;  // + mf*1024 + ks*8192
  const char* bB = (const char*)Bs + (wn*32 + l16)*64 + sw*16;  // + nf*1024 + ks*4096

  f32x4 acc[4][2];
  #pragma unroll
  for (int i=0;i<4;i++)
    #pragma unroll
    for (int j=0;j<2;j++) acc[i][j] = (f32x4){0.f,0.f,0.f,0.f};

  const size_t rA0 = (size_t)(16*wave)*K;
  const size_t rA1 = (size_t)(16*(wave+4))*K;

  for (int k0 = 0; k0 < K; k0 += 64) {
    __syncthreads();                       // prev fragments consumed
    async16(dA0,        pa + rA0 + k0);            // ks0
    async16(dA1,        pa + rA1 + k0);
    async16(dB0,        pb + rA0 + k0);
    async16(dA0 + 4096, pa + rA0 + k0 + 32);       // ks1
    async16(dA1 + 4096, pa + rA1 + k0 + 32);
    async16(dB0 + 2048, pb + rA0 + k0 + 32);
    __syncthreads();                       // staging drained (compiler vmcnt)

    #pragma unroll
    for (int ks=0; ks<2; ks++){
      bf16x8 afr[4], bfr[2];
      #pragma unroll
      for (int mf=0; mf<4; mf++)
        afr[mf] = *reinterpret_cast<const bf16x8*>(aB + ks*8192 + mf*1024);
      #pragma unroll
      for (int nf=0; nf<2; nf++)
        bfr[nf] = *reinterpret_cast<const bf16x8*>(bB + ks*4096 + nf*1024);
      #pragma unroll
      for (int mf=0; mf<4; mf++)
        #pragma unroll
        for (int nf=0; nf<2; nf++)
          acc[mf][nf] = __builtin_amdgcn_mfma_f32_16x16x32_bf16(afr[mf], bfr[nf], acc[mf][nf], 0, 0, 0);
    }
  }

  // ---- epilogue ----
  #pragma unroll
  for (int mf=0; mf<4; mf++){
    #pragma unroll
    for (int nf=0; nf<2; nf++){
      const int col = n0 + wn*32 + nf*16 + l16;
      #pragma unroll
      for (int j=0;j<4;j++){
        const int row = m0 + wm*64 + mf*16 + quad*4 + j;
        float v = acc[mf][nf][j];
        if (EPI == 1) {
          v += bias[col];
          v = (v > 20.f) ? v : log1pf(__expf(v));
          ((u16*)outv)[(size_t)row*N + col] = f2h(v);       // delta fp16
        } else if (EPI == 2) {
          v += resid[(size_t)row*N + col];
          ((float*)outv)[(size_t)row*N + col] = v;          // final out fp32
        } else {
          ((u16*)outv)[(size_t)row*N + col] = f2b(v);       // bf16 activation
        }
      }
    }
  }
}

// ---------------------------------------------------------------------------
// Causal depthwise conv(width 4) + bias + SiLU, 8 channels/thread vectorized.
// ---------------------------------------------------------------------------
__global__ __launch_bounds__(256) void conv_silu_kernel(
    const u16* __restrict__ xz, const float* __restrict__ cw,
    const float* __restrict__ cb, u16* __restrict__ u)
{
  const int idx = blockIdx.x*256 + threadIdx.x;   // (bt, c-group)
  const int c0 = (idx & 255) * 8;
  const int bt = idx >> 8;
  const int t  = bt & (SEQLEN-1);
  float acc[8];
  #pragma unroll
  for (int j=0;j<8;j++) acc[j] = cb[c0+j];
  #pragma unroll
  for (int k=0;k<4;k++){
    if (t - 3 + k >= 0){
      bf16x8 xv = *reinterpret_cast<const bf16x8*>(xz + (size_t)(bt-3+k)*4096 + c0);
      #pragma unroll
      for (int j=0;j<8;j++)
        acc[j] = fmaf(cw[(c0+j)*4 + k], (float)xv[j], acc[j]);
    }
  }
  u16 o[8];
  #pragma unroll
  for (int j=0;j<8;j++){
    float sv = acc[j] / (1.f + __expf(-acc[j]));
    o[j] = f2b(sv);
  }
  __builtin_memcpy(u + (size_t)bt*D_INNER + c0, o, 16);
}

// ---------------------------------------------------------------------------
// x_proj (cols 16..31 only): one wave per row, lane=(kq,n), bf16x8 both streams.
// ---------------------------------------------------------------------------
__global__ __launch_bounds__(256) void xproj_kernel(
    const u16* __restrict__ u, const u16* __restrict__ Wxt, float* __restrict__ Bm)
{
  const int wave = threadIdx.x >> 6, lane = threadIdx.x & 63;
  const int m = blockIdx.x*4 + wave;
  const int n = lane & 15, kq = lane >> 4;
  const u16* ur = u   + (size_t)m*D_INNER + kq*512;
  const u16* wr = Wxt + (size_t)n*D_INNER + kq*512;
  float acc = 0.f;
  #pragma unroll 4
  for (int i=0;i<512;i+=8){
    bf16x8 uv = *reinterpret_cast<const bf16x8*>(ur + i);
    bf16x8 wv = *reinterpret_cast<const bf16x8*>(wr + i);
    #pragma unroll
    for (int j=0;j<8;j++) acc = fmaf((float)uv[j], (float)wv[j], acc);
  }
  acc += __shfl_xor(acc, 16);
  acc += __shfl_xor(acc, 32);
  if (lane < 16) Bm[(size_t)m*16 + n] = acc;
}

// ---------------------------------------------------------------------------
// Chunked selective scan, 3 passes (exact linear-recurrence decomposition).
// ---------------------------------------------------------------------------
__global__ __launch_bounds__(256) void scan_partial(
    const u16* __restrict__ uu, const u16* __restrict__ delta16,
    const float* __restrict__ Bm, const float* __restrict__ Alog,
    float* __restrict__ hend, float* __restrict__ sumdt)
{
  const int b = blockIdx.y, ch = blockIdx.z;
  const int c = blockIdx.x*256 + threadIdx.x;
  const int row0 = b*SEQLEN + ch*CHUNK;
  float A[16], h[16];
  #pragma unroll
  for (int s=0;s<16;s++){ A[s] = -__expf(Alog[c*16+s]); h[s]=0.f; }
  __shared__ float Bsh[CHUNK*16];
  const float* src = Bm + (size_t)row0*16;
  #pragma unroll
  for (int j=0;j<8;j++) Bsh[threadIdx.x + 256*j] = src[threadIdx.x + 256*j];
  __syncthreads();

  float S = 0.f;
  float dta[8], uva[8], dtb[8], uvb[8];
  #pragma unroll
  for (int j=0;j<8;j++){
    size_t r = (size_t)(row0+j);
    dta[j] = h2f(delta16[r*D_INNER+c]);
    uva[j] = b2f(uu[r*D_INNER+c]);
  }
  #pragma unroll 1
  for (int g=0; g<CHUNK; g+=16){
    #pragma unroll
    for (int j=0;j<8;j++){
      int tl = g+8+j; tl = tl < CHUNK ? tl : CHUNK-1;
      size_t r = (size_t)(row0+tl);
      dtb[j] = h2f(delta16[r*D_INNER+c]);
      uvb[j] = b2f(uu[r*D_INNER+c]);
    }
    #pragma unroll
    for (int j=0;j<8;j++){
      float dt=dta[j], uv=uva[j]; S += dt; float xv=dt*uv;
      const float* Bt = &Bsh[(g+j)*16];
      #pragma unroll
      for (int s=0;s<16;s++) h[s] = fmaf(h[s], __expf(dt*A[s]), xv*Bt[s]);
    }
    #pragma unroll
    for (int j=0;j<8;j++){
      int tl = g+16+j; tl = tl < CHUNK ? tl : CHUNK-1;
      size_t r = (size_t)(row0+tl);
      dta[j] = h2f(delta16[r*D_INNER+c]);
      uva[j] = b2f(uu[r*D_INNER+c]);
    }
    #pragma unroll
    for (int j=0;j<8;j++){
      float dt=dtb[j], uv=uvb[j]; S += dt; float xv=dt*uv;
      const float* Bt = &Bsh[(g+8+j)*16];
      #pragma unroll
      for (int s=0;s<16;s++) h[s] = fmaf(h[s], __expf(dt*A[s]), xv*Bt[s]);
    }
  }
  const size_t base = ((size_t)(b*NCHUNK+ch)*16)*D_INNER + c;
  #pragma unroll
  for (int s=0;s<16;s++) hend[base + (size_t)s*D_INNER] = h[s];
  sumdt[(size_t)(b*NCHUNK+ch)*D_INNER + c] = S;
}

__global__ __launch_bounds__(256) void scan_combine(
    const float* __restrict__ hend, const float* __restrict__ sumdt,
    const float* __restrict__ Alog, float* __restrict__ hin)
{
  const int b = blockIdx.y;
  const int c = blockIdx.x*256 + threadIdx.x;
  float A[16], h[16];
  #pragma unroll
  for (int s=0;s<16;s++){ A[s] = -__expf(Alog[c*16+s]); h[s]=0.f; }
  #pragma unroll 1
  for (int k=0;k<NCHUNK;k++){
    const size_t base = ((size_t)(b*NCHUNK+k)*16)*D_INNER + c;
    #pragma unroll
    for (int s=0;s<16;s++) hin[base + (size_t)s*D_INNER] = h[s];
    const float S = sumdt[(size_t)(b*NCHUNK+k)*D_INNER + c];
    #pragma unroll
    for (int s=0;s<16;s++)
      h[s] = fmaf(h[s], __expf(S*A[s]), hend[base + (size_t)s*D_INNER]);
  }
}

__global__ __launch_bounds__(256) void scan_final(
    const u16* __restrict__ uu, const u16* __restrict__ delta16,
    const float* __restrict__ Bm, const u16* __restrict__ xz,
    const float* __restrict__ Alog, const float* __restrict__ Dpar,
    const float* __restrict__ hin, u16* __restrict__ yg)
{
  const int b = blockIdx.y, ch = blockIdx.z;
  const int c = blockIdx.x*256 + threadIdx.x;
  const int row0 = b*SEQLEN + ch*CHUNK;
  float A[16], h[16];
  const size_t base = ((size_t)(b*NCHUNK+ch)*16)*D_INNER + c;
  #pragma unroll
  for (int s=0;s<16;s++){
    A[s] = -__expf(Alog[c*16+s]);
    h[s] = hin[base + (size_t)s*D_INNER];
  }
  const float Dc = Dpar[c];
  __shared__ float Bsh[CHUNK*16];
  const float* src = Bm + (size_t)row0*16;
  #pragma unroll
  for (int j=0;j<8;j++) Bsh[threadIdx.x + 256*j] = src[threadIdx.x + 256*j];
  __syncthreads();

  float dta[8], uva[8], zva[8], dtb[8], uvb[8], zvb[8];
  #pragma unroll
  for (int j=0;j<8;j++){
    size_t r = (size_t)(row0+j);
    dta[j] = h2f(delta16[r*D_INNER+c]);
    uva[j] = b2f(uu[r*D_INNER+c]);
    zva[j] = b2f(xz[r*4096 + D_INNER + c]);
  }
  #pragma unroll 1
  for (int g=0; g<CHUNK; g+=16){
    #pragma unroll
    for (int j=0;j<8;j++){
      int tl = g+8+j; tl = tl < CHUNK ? tl : CHUNK-1;
      size_t r = (size_t)(row0+tl);
      dtb[j] = h2f(delta16[r*D_INNER+c]);
      uvb[j] = b2f(uu[r*D_INNER+c]);
      zvb[j] = b2f(xz[r*4096 + D_INNER + c]);
    }
    #pragma unroll
    for (int j=0;j<8;j++){
      float dt=dta[j], uv=uva[j], zv=zva[j];
      float xv=dt*uv, y=0.f;
      const float* Bt = &Bsh[(g+j)*16];
      #pragma unroll
      for (int s=0;s<16;s++){
        h[s] = fmaf(h[s], __expf(dt*A[s]), xv*Bt[s]);
        y += h[s];
      }
      y = fmaf(uv, Dc, y);
      float gz = zv/(1.f+__expf(-zv));
      yg[(size_t)(row0+g+j)*D_INNER + c] = f2b(y*gz);
    }
    #pragma unroll
    for (int j=0;j<8;j++){
      int tl = g+16+j; tl = tl < CHUNK ? tl : CHUNK-1;
      size_t r = (size_t)(row0+tl);
      dta[j] = h2f(delta16[r*D_INNER+c]);
      uva[j] = b2f(uu[r*D_INNER+c]);
      zva[j] = b2f(xz[r*4096 + D_INNER + c]);
    }
    #pragma unroll
    for (int j=0;j<8;j++){
      float dt=dtb[j], uv=uvb[j], zv=zvb[j];
      float xv=dt*uv, y=0.f;
      const float* Bt = &Bsh[(g+8+j)*16];
      #pragma unroll
      for (int s=0;s<16;s++){
        h[s] = fmaf(h[s], __expf(dt*A[s]), xv*Bt[s]);
        y += h[s];
      }
      y = fmaf(uv, Dc, y);
      float gz = zv/(1.f+__expf(-zv));
      yg[(size_t)(row0+g+8+j)*D_INNER + c] = f2b(y*gz);
    }
  }
}

// ---------------------------------------------------------------------------
extern "C" void kernel_launch(void* const* d_in, const int* in_sizes, int n_in,
                              void* d_out, int out_size, void* d_ws, size_t ws_size,
                              hipStream_t stream)
{
  const float* x    = (const float*)d_in[0];
  const float* lng  = (const float*)d_in[1];
  const float* lnb  = (const float*)d_in[2];
  const float* W1   = (const float*)d_in[3];
  const float* cw   = (const float*)d_in[4];
  const float* cb   = (const float*)d_in[5];
  const float* Wx   = (const float*)d_in[6];
  const float* Wdt  = (const float*)d_in[7];
  const float* dtb  = (const float*)d_in[8];
  const float* Alog = (const float*)d_in[9];
  const float* Dpar = (const float*)d_in[10];
  const float* Wout = (const float*)d_in[11];

  // workspace layout (MiB offsets), total ~199 MiB
  char* ws = (char*)d_ws;
  u16*   dlt   = (u16*)(ws);
  u16*   xn    = (u16*)(ws);                 // alias (sequenced)
  u16*   xz    = (u16*)(ws + (32llu<<20));
  u16*   uu    = (u16*)(ws + (96llu<<20));
  float* Bm    = (float*)(ws + (128llu<<20));
  u16*   W1t   = (u16*)(ws + (129llu<<20));
  u16*   Wdtt  = (u16*)(ws + (137llu<<20));
  u16*   Woutt = (u16*)(ws + (145llu<<20));
  u16*   yg    = (u16*)(ws + (149llu<<20));
  float* hend  = (float*)(ws + (181llu<<20));
  float* sumdt = (float*)(ws + (189llu<<20));
  float* hin   = (float*)(ws + (190llu<<20));
  u16*   Wxt   = (u16*)(ws + (198llu<<20));

  // weights -> bf16, transposed to [N][K]
  wcvt_t_kernel<<<dim3(2*D_INNER/32, D_MODEL/32), 256, 0, stream>>>(W1,  W1t,  D_MODEL, 2*D_INNER);
  wcvt_t_kernel<<<dim3(D_INNER/32,  D_INNER/32), 256, 0, stream>>>(Wdt, Wdtt, D_INNER, D_INNER);
  wcvt_t_kernel<<<dim3(D_MODEL/32,  D_INNER/32), 256, 0, stream>>>(Wout,Woutt,D_INNER, D_MODEL);
  wxcvt_kernel<<<D_INNER/256, 256, 0, stream>>>(Wx, Wxt);

  ln_kernel<<<NROWS, 256, 0, stream>>>(x, lng, lnb, xn);

  {
    const int gx = 2*D_INNER/64, gy = NROWS/128;   // 64 x 64 = 4096 blocks
    gemm_bn64<0><<<gx*gy, 256, 0, stream>>>(
        xn, W1t, nullptr, nullptr, (void*)xz, NROWS, 2*D_INNER, D_MODEL, gx, gy);
  }

  conv_silu_kernel<<<(NROWS*D_INNER/8)/256, 256, 0, stream>>>(xz, cw, cb, uu);

  xproj_kernel<<<NROWS/4, 256, 0, stream>>>(uu, Wxt, Bm);

  {
    const int gx = D_INNER/64, gy = NROWS/128;     // 32 x 64 = 2048 blocks
    gemm_bn64<1><<<gx*gy, 256, 0, stream>>>(
        uu, Wdtt, dtb, nullptr, (void*)dlt, NROWS, D_INNER, D_INNER, gx, gy);
  }

  scan_partial<<<dim3(D_INNER/256, BATCH, NCHUNK), 256, 0, stream>>>(
      uu, dlt, Bm, Alog, hend, sumdt);
  scan_combine<<<dim3(D_INNER/256, BATCH), 256, 0, stream>>>(
      hend, sumdt, Alog, hin);
  scan_final<<<dim3(D_INNER/256, BATCH, NCHUNK), 256, 0, stream>>>(
      uu, dlt, Bm, xz, Alog, Dpar, hin, yg);

  {
    const int gx = D_MODEL/64, gy = NROWS/128;     // 16 x 64 = 1024 blocks
    gemm_bn64<2><<<gx*gy, 256, 0, stream>>>(
        yg, Woutt, nullptr, x, d_out, NROWS, D_MODEL, D_INNER, gx, gy);
  }

  (void)in_sizes; (void)n_in; (void)out_size; (void)ws_size;
}

// Round 4
// 797.159 us; speedup vs baseline: 1.2223x; 1.1075x over previous
//
#include <hip/hip_runtime.h>

typedef unsigned short u16;
typedef unsigned int   u32;

#define D_MODEL 1024
#define D_INNER 2048
#define D_STATE 16
#define SEQLEN  2048
#define BATCH   4
#define NROWS   (BATCH*SEQLEN)   // 8192
#define CHUNK   128
#define NCHUNK  (SEQLEN/CHUNK)   // 16

__device__ __forceinline__ float b2f(u16 v){
  union { u32 i; float f; } u; u.i = ((u32)v) << 16; return u.f;
}
__device__ __forceinline__ u16 f2b(float f){
  union { float f; u32 i; } u; u.f = f;
  u32 x = u.i;
  return (u16)((x + 0x7fffu + ((x >> 16) & 1u)) >> 16);  // RNE
}
__device__ __forceinline__ float h2f(u16 v){
  _Float16 h; __builtin_memcpy(&h, &v, 2); return (float)h;
}
__device__ __forceinline__ u16 f2h(float f){
  _Float16 h = (_Float16)f; u16 v; __builtin_memcpy(&v, &h, 2); return v;
}

typedef __bf16 bf16x8 __attribute__((ext_vector_type(8)));
typedef float  f32x4  __attribute__((ext_vector_type(4)));

// async global->LDS, 16B per lane; data for lane i lands at lds + i*16B.
__device__ __forceinline__ void async16(u16* lds, const u16* g){
  __builtin_amdgcn_global_load_lds(
      (const __attribute__((address_space(1))) void*)g,
      (__attribute__((address_space(3))) void*)lds,
      16, 0, 0);
}

// ---------------------------------------------------------------------------
// fp32 [Kd][Nd] -> bf16 transposed [Nd][Kd]   (32x32 LDS tiles)
// ---------------------------------------------------------------------------
__global__ __launch_bounds__(256) void wcvt_t_kernel(
    const float* __restrict__ W, u16* __restrict__ Bt, int Kd, int Nd)
{
  __shared__ u16 tile[32][33];
  const int n0 = blockIdx.x*32, k0 = blockIdx.y*32;
  const int tx = threadIdx.x & 31, ty = threadIdx.x >> 5;  // ty 0..7
  #pragma unroll
  for (int i=0;i<32;i+=8)
    tile[ty+i][tx] = f2b(W[(size_t)(k0+ty+i)*Nd + n0+tx]);   // tile[k][n]
  __syncthreads();
  #pragma unroll
  for (int i=0;i<32;i+=8)
    Bt[(size_t)(n0+ty+i)*Kd + k0+tx] = tile[tx][ty+i];
}

// Wx [2048][32] cols 16..31 -> Wxt bf16 [16][2048]
__global__ __launch_bounds__(256) void wxcvt_kernel(
    const float* __restrict__ Wx, u16* __restrict__ Wxt)
{
  const int k = blockIdx.x*256 + threadIdx.x;   // 0..2047
  #pragma unroll
  for (int n=0;n<16;n++)
    Wxt[n*D_INNER + k] = f2b(Wx[(size_t)k*32 + 16 + n]);
}

// ---------------------------------------------------------------------------
// Fused LayerNorm: x[row][1024] fp32 -> xn bf16
// ---------------------------------------------------------------------------
__global__ __launch_bounds__(256) void ln_kernel(
    const float* __restrict__ x, const float* __restrict__ g,
    const float* __restrict__ be, u16* __restrict__ xn)
{
  const int row = blockIdx.x;
  const float* xr = x + (size_t)row * D_MODEL;
  const int tid = threadIdx.x;
  float v[4]; float s = 0.f, s2 = 0.f;
  #pragma unroll
  for (int j=0;j<4;j++){
    float f = xr[tid + 256*j];
    v[j] = f; s += f; s2 += f*f;
  }
  #pragma unroll
  for (int o=32;o>0;o>>=1){ s += __shfl_down(s,o); s2 += __shfl_down(s2,o); }
  __shared__ float sh[8];
  const int wave = tid>>6, lane = tid&63;
  if (lane==0){ sh[wave]=s; sh[4+wave]=s2; }
  __syncthreads();
  const float ts  = sh[0]+sh[1]+sh[2]+sh[3];
  const float ts2 = sh[4]+sh[5]+sh[6]+sh[7];
  const float mu  = ts * (1.f/D_MODEL);
  const float var = ts2 * (1.f/D_MODEL) - mu*mu;
  const float rstd = rsqrtf(var + 1e-5f);
  u16* xo = xn + (size_t)row * D_MODEL;
  #pragma unroll
  for (int j=0;j<4;j++){
    int i = tid + 256*j;
    xo[i] = f2b((v[j]-mu)*rstd * g[i] + be[i]);
  }
}

// ---------------------------------------------------------------------------
// 128x128 MFMA GEMM, BK=32 (m103-replica operating point).
// Per-CU stream law (R0-R3 + m103 data): each resident block-stream sustains
// ~6.5 B/cyc staging; MfmaUtil ~= S * 6.5 * (FLOP/B) / 3377.  128^2 gives
// FLOP/B=64; BK=32 keeps LDS at 16 KB and regs at ~148 total (84 VGPR + 64
// acc) -> S=3 streams/CU (vs BK=64's 32 KB + S=2 at MfmaUtil 20%).
// Simple 2-barrier loop; latency hiding via inter-block TLP (m114).
// Swizzle: 16B-granule XOR (verified 0-conflict): pre-swizzled global source
// (linear global_load_lds dest), swizzled ds_read on the read side.
// A [M][K] bf16 ; Bt [N][K] bf16 (pre-transposed). 4 waves, 64x64 per wave.
// EPI 0: bf16 ; EPI 1: softplus(v+bias)->fp16 ; EPI 2: v+resid->fp32
// ---------------------------------------------------------------------------
template<int EPI>
__global__ __launch_bounds__(256) void gemm_bk32(
    const u16* __restrict__ A, const u16* __restrict__ Bt,
    const float* __restrict__ bias, const float* __restrict__ resid,
    void* __restrict__ outv, int M, int N, int K, int gx, int gy)
{
  __shared__ __align__(16) u16 As[128*32];   // 8 KB
  __shared__ __align__(16) u16 Bs[128*32];   // 8 KB
  const int tid  = threadIdx.x;
  const int wave = tid >> 6, lane = tid & 63;
  const int quad = lane >> 4, l16 = lane & 15;

  // XCD swizzle: consecutive blocks on one XCD share the same n-column.
  const int lid = blockIdx.x;
  const int xcd = lid & 7, q = lid >> 3;
  const int cpx = gx >> 3;
  const int qd  = q / gy;
  const int bx  = xcd*cpx + qd;
  const int by  = q - qd*gy;
  const int m0 = by*128, n0 = bx*128;
  const int wm = (wave & 1)*64, wn = (wave >> 1)*64;

  // staging: wave covers rows wave*32..+31 of both tiles
  const int srow = wave*32 + (lane >> 2);
  const int gcol = ((lane & 3) ^ ((lane >> 3) & 3)) * 8;  // swizzled granule
  const u16* pA = A  + (size_t)(m0 + srow)*K + gcol;
  const u16* pB = Bt + (size_t)(n0 + srow)*K + gcol;
  u16* lA = &As[(wave*32)*32];
  u16* lB = &Bs[(wave*32)*32];

  // fragment LDS byte offsets
  const int sw   = quad ^ ((l16 >> 1) & 3);
  const int aoff = (wm + l16)*64 + sw*16;   // + mf*1024
  const int boff = (wn + l16)*64 + sw*16;   // + nf*1024

  f32x4 acc[4][4];
  #pragma unroll
  for (int i=0;i<4;i++)
    #pragma unroll
    for (int j=0;j<4;j++) acc[i][j] = (f32x4){0.f,0.f,0.f,0.f};

  for (int k0 = 0; k0 < K; k0 += 32) {
    __syncthreads();                       // prev fragments consumed
    async16(lA,          pA + k0);
    async16(lA + 16*32,  pA + (size_t)16*K + k0);
    async16(lB,          pB + k0);
    async16(lB + 16*32,  pB + (size_t)16*K + k0);
    __syncthreads();                       // staging drained

    bf16x8 afr[4], bfr[4];
    #pragma unroll
    for (int mf=0; mf<4; mf++)
      afr[mf] = *reinterpret_cast<const bf16x8*>((const char*)As + aoff + mf*1024);
    #pragma unroll
    for (int nf=0; nf<4; nf++)
      bfr[nf] = *reinterpret_cast<const bf16x8*>((const char*)Bs + boff + nf*1024);
    #pragma unroll
    for (int mf=0; mf<4; mf++)
      #pragma unroll
      for (int nf=0; nf<4; nf++)
        acc[mf][nf] = __builtin_amdgcn_mfma_f32_16x16x32_bf16(afr[mf], bfr[nf], acc[mf][nf], 0, 0, 0);
  }

  #pragma unroll
  for (int mf=0; mf<4; mf++){
    #pragma unroll
    for (int nf=0; nf<4; nf++){
      const int col = n0 + wn + nf*16 + l16;
      #pragma unroll
      for (int j=0;j<4;j++){
        const int row = m0 + wm + mf*16 + quad*4 + j;
        float v = acc[mf][nf][j];
        if (EPI == 1) {
          v += bias[col];
          v = (v > 20.f) ? v : log1pf(__expf(v));
          ((u16*)outv)[(size_t)row*N + col] = f2h(v);       // delta fp16
        } else if (EPI == 2) {
          v += resid[(size_t)row*N + col];
          ((float*)outv)[(size_t)row*N + col] = v;          // final out fp32
        } else {
          ((u16*)outv)[(size_t)row*N + col] = f2b(v);       // bf16 activation
        }
      }
    }
  }
}

// ---------------------------------------------------------------------------
// Causal depthwise conv(width 4) + bias + SiLU, 8 channels/thread vectorized.
// ---------------------------------------------------------------------------
__global__ __launch_bounds__(256) void conv_silu_kernel(
    const u16* __restrict__ xz, const float* __restrict__ cw,
    const float* __restrict__ cb, u16* __restrict__ u)
{
  const int idx = blockIdx.x*256 + threadIdx.x;   // (bt, c-group)
  const int c0 = (idx & 255) * 8;
  const int bt = idx >> 8;
  const int t  = bt & (SEQLEN-1);
  float acc[8];
  #pragma unroll
  for (int j=0;j<8;j++) acc[j] = cb[c0+j];
  #pragma unroll
  for (int k=0;k<4;k++){
    if (t - 3 + k >= 0){
      bf16x8 xv = *reinterpret_cast<const bf16x8*>(xz + (size_t)(bt-3+k)*4096 + c0);
      #pragma unroll
      for (int j=0;j<8;j++)
        acc[j] = fmaf(cw[(c0+j)*4 + k], (float)xv[j], acc[j]);
    }
  }
  u16 o[8];
  #pragma unroll
  for (int j=0;j<8;j++){
    float sv = acc[j] / (1.f + __expf(-acc[j]));
    o[j] = f2b(sv);
  }
  __builtin_memcpy(u + (size_t)bt*D_INNER + c0, o, 16);
}

// ---------------------------------------------------------------------------
// x_proj (cols 16..31 only): one wave per row, lane=(kq,n), bf16x8 both streams.
// ---------------------------------------------------------------------------
__global__ __launch_bounds__(256) void xproj_kernel(
    const u16* __restrict__ u, const u16* __restrict__ Wxt, float* __restrict__ Bm)
{
  const int wave = threadIdx.x >> 6, lane = threadIdx.x & 63;
  const int m = blockIdx.x*4 + wave;
  const int n = lane & 15, kq = lane >> 4;
  const u16* ur = u   + (size_t)m*D_INNER + kq*512;
  const u16* wr = Wxt + (size_t)n*D_INNER + kq*512;
  float acc = 0.f;
  #pragma unroll 4
  for (int i=0;i<512;i+=8){
    bf16x8 uv = *reinterpret_cast<const bf16x8*>(ur + i);
    bf16x8 wv = *reinterpret_cast<const bf16x8*>(wr + i);
    #pragma unroll
    for (int j=0;j<8;j++) acc = fmaf((float)uv[j], (float)wv[j], acc);
  }
  acc += __shfl_xor(acc, 16);
  acc += __shfl_xor(acc, 32);
  if (lane < 16) Bm[(size_t)m*16 + n] = acc;
}

// ---------------------------------------------------------------------------
// Chunked selective scan, 3 passes (exact linear-recurrence decomposition).
// ---------------------------------------------------------------------------
__global__ __launch_bounds__(256) void scan_partial(
    const u16* __restrict__ uu, const u16* __restrict__ delta16,
    const float* __restrict__ Bm, const float* __restrict__ Alog,
    float* __restrict__ hend, float* __restrict__ sumdt)
{
  const int b = blockIdx.y, ch = blockIdx.z;
  const int c = blockIdx.x*256 + threadIdx.x;
  const int row0 = b*SEQLEN + ch*CHUNK;
  float A[16], h[16];
  #pragma unroll
  for (int s=0;s<16;s++){ A[s] = -__expf(Alog[c*16+s]); h[s]=0.f; }
  __shared__ float Bsh[CHUNK*16];
  const float* src = Bm + (size_t)row0*16;
  #pragma unroll
  for (int j=0;j<8;j++) Bsh[threadIdx.x + 256*j] = src[threadIdx.x + 256*j];
  __syncthreads();

  float S = 0.f;
  float dta[8], uva[8], dtb[8], uvb[8];
  #pragma unroll
  for (int j=0;j<8;j++){
    size_t r = (size_t)(row0+j);
    dta[j] = h2f(delta16[r*D_INNER+c]);
    uva[j] = b2f(uu[r*D_INNER+c]);
  }
  #pragma unroll 1
  for (int g=0; g<CHUNK; g+=16){
    #pragma unroll
    for (int j=0;j<8;j++){
      int tl = g+8+j; tl = tl < CHUNK ? tl : CHUNK-1;
      size_t r = (size_t)(row0+tl);
      dtb[j] = h2f(delta16[r*D_INNER+c]);
      uvb[j] = b2f(uu[r*D_INNER+c]);
    }
    #pragma unroll
    for (int j=0;j<8;j++){
      float dt=dta[j], uv=uva[j]; S += dt; float xv=dt*uv;
      const float* Bt = &Bsh[(g+j)*16];
      #pragma unroll
      for (int s=0;s<16;s++) h[s] = fmaf(h[s], __expf(dt*A[s]), xv*Bt[s]);
    }
    #pragma unroll
    for (int j=0;j<8;j++){
      int tl = g+16+j; tl = tl < CHUNK ? tl : CHUNK-1;
      size_t r = (size_t)(row0+tl);
      dta[j] = h2f(delta16[r*D_INNER+c]);
      uva[j] = b2f(uu[r*D_INNER+c]);
    }
    #pragma unroll
    for (int j=0;j<8;j++){
      float dt=dtb[j], uv=uvb[j]; S += dt; float xv=dt*uv;
      const float* Bt = &Bsh[(g+8+j)*16];
      #pragma unroll
      for (int s=0;s<16;s++) h[s] = fmaf(h[s], __expf(dt*A[s]), xv*Bt[s]);
    }
  }
  const size_t base = ((size_t)(b*NCHUNK+ch)*16)*D_INNER + c;
  #pragma unroll
  for (int s=0;s<16;s++) hend[base + (size_t)s*D_INNER] = h[s];
  sumdt[(size_t)(b*NCHUNK+ch)*D_INNER + c] = S;
}

__global__ __launch_bounds__(256) void scan_combine(
    const float* __restrict__ hend, const float* __restrict__ sumdt,
    const float* __restrict__ Alog, float* __restrict__ hin)
{
  const int b = blockIdx.y;
  const int c = blockIdx.x*256 + threadIdx.x;
  float A[16], h[16];
  #pragma unroll
  for (int s=0;s<16;s++){ A[s] = -__expf(Alog[c*16+s]); h[s]=0.f; }
  #pragma unroll 1
  for (int k=0;k<NCHUNK;k++){
    const size_t base = ((size_t)(b*NCHUNK+k)*16)*D_INNER + c;
    #pragma unroll
    for (int s=0;s<16;s++) hin[base + (size_t)s*D_INNER] = h[s];
    const float S = sumdt[(size_t)(b*NCHUNK+k)*D_INNER + c];
    #pragma unroll
    for (int s=0;s<16;s++)
      h[s] = fmaf(h[s], __expf(S*A[s]), hend[base + (size_t)s*D_INNER]);
  }
}

__global__ __launch_bounds__(256) void scan_final(
    const u16* __restrict__ uu, const u16* __restrict__ delta16,
    const float* __restrict__ Bm, const u16* __restrict__ xz,
    const float* __restrict__ Alog, const float* __restrict__ Dpar,
    const float* __restrict__ hin, u16* __restrict__ yg)
{
  const int b = blockIdx.y, ch = blockIdx.z;
  const int c = blockIdx.x*256 + threadIdx.x;
  const int row0 = b*SEQLEN + ch*CHUNK;
  float A[16], h[16];
  const size_t base = ((size_t)(b*NCHUNK+ch)*16)*D_INNER + c;
  #pragma unroll
  for (int s=0;s<16;s++){
    A[s] = -__expf(Alog[c*16+s]);
    h[s] = hin[base + (size_t)s*D_INNER];
  }
  const float Dc = Dpar[c];
  __shared__ float Bsh[CHUNK*16];
  const float* src = Bm + (size_t)row0*16;
  #pragma unroll
  for (int j=0;j<8;j++) Bsh[threadIdx.x + 256*j] = src[threadIdx.x + 256*j];
  __syncthreads();

  float dta[8], uva[8], zva[8], dtb[8], uvb[8], zvb[8];
  #pragma unroll
  for (int j=0;j<8;j++){
    size_t r = (size_t)(row0+j);
    dta[j] = h2f(delta16[r*D_INNER+c]);
    uva[j] = b2f(uu[r*D_INNER+c]);
    zva[j] = b2f(xz[r*4096 + D_INNER + c]);
  }
  #pragma unroll 1
  for (int g=0; g<CHUNK; g+=16){
    #pragma unroll
    for (int j=0;j<8;j++){
      int tl = g+8+j; tl = tl < CHUNK ? tl : CHUNK-1;
      size_t r = (size_t)(row0+tl);
      dtb[j] = h2f(delta16[r*D_INNER+c]);
      uvb[j] = b2f(uu[r*D_INNER+c]);
      zvb[j] = b2f(xz[r*4096 + D_INNER + c]);
    }
    #pragma unroll
    for (int j=0;j<8;j++){
      float dt=dta[j], uv=uva[j], zv=zva[j];
      float xv=dt*uv, y=0.f;
      const float* Bt = &Bsh[(g+j)*16];
      #pragma unroll
      for (int s=0;s<16;s++){
        h[s] = fmaf(h[s], __expf(dt*A[s]), xv*Bt[s]);
        y += h[s];
      }
      y = fmaf(uv, Dc, y);
      float gz = zv/(1.f+__expf(-zv));
      yg[(size_t)(row0+g+j)*D_INNER + c] = f2b(y*gz);
    }
    #pragma unroll
    for (int j=0;j<8;j++){
      int tl = g+16+j; tl = tl < CHUNK ? tl : CHUNK-1;
      size_t r = (size_t)(row0+tl);
      dta[j] = h2f(delta16[r*D_INNER+c]);
      uva[j] = b2f(uu[r*D_INNER+c]);
      zva[j] = b2f(xz[r*4096 + D_INNER + c]);
    }
    #pragma unroll
    for (int j=0;j<8;j++){
      float dt=dtb[j], uv=uvb[j], zv=zvb[j];
      float xv=dt*uv, y=0.f;
      const float* Bt = &Bsh[(g+8+j)*16];
      #pragma unroll
      for (int s=0;s<16;s++){
        h[s] = fmaf(h[s], __expf(dt*A[s]), xv*Bt[s]);
        y += h[s];
      }
      y = fmaf(uv, Dc, y);
      float gz = zv/(1.f+__expf(-zv));
      yg[(size_t)(row0+g+8+j)*D_INNER + c] = f2b(y*gz);
    }
  }
}

// ---------------------------------------------------------------------------
extern "C" void kernel_launch(void* const* d_in, const int* in_sizes, int n_in,
                              void* d_out, int out_size, void* d_ws, size_t ws_size,
                              hipStream_t stream)
{
  const float* x    = (const float*)d_in[0];
  const float* lng  = (const float*)d_in[1];
  const float* lnb  = (const float*)d_in[2];
  const float* W1   = (const float*)d_in[3];
  const float* cw   = (const float*)d_in[4];
  const float* cb   = (const float*)d_in[5];
  const float* Wx   = (const float*)d_in[6];
  const float* Wdt  = (const float*)d_in[7];
  const float* dtb  = (const float*)d_in[8];
  const float* Alog = (const float*)d_in[9];
  const float* Dpar = (const float*)d_in[10];
  const float* Wout = (const float*)d_in[11];

  // workspace layout (MiB offsets), total ~199 MiB
  char* ws = (char*)d_ws;
  u16*   dlt   = (u16*)(ws);
  u16*   xn    = (u16*)(ws);                 // alias (sequenced)
  u16*   xz    = (u16*)(ws + (32llu<<20));
  u16*   uu    = (u16*)(ws + (96llu<<20));
  float* Bm    = (float*)(ws + (128llu<<20));
  u16*   W1t   = (u16*)(ws + (129llu<<20));
  u16*   Wdtt  = (u16*)(ws + (137llu<<20));
  u16*   Woutt = (u16*)(ws + (145llu<<20));
  u16*   yg    = (u16*)(ws + (149llu<<20));
  float* hend  = (float*)(ws + (181llu<<20));
  float* sumdt = (float*)(ws + (189llu<<20));
  float* hin   = (float*)(ws + (190llu<<20));
  u16*   Wxt   = (u16*)(ws + (198llu<<20));

  // weights -> bf16, transposed to [N][K]
  wcvt_t_kernel<<<dim3(2*D_INNER/32, D_MODEL/32), 256, 0, stream>>>(W1,  W1t,  D_MODEL, 2*D_INNER);
  wcvt_t_kernel<<<dim3(D_INNER/32,  D_INNER/32), 256, 0, stream>>>(Wdt, Wdtt, D_INNER, D_INNER);
  wcvt_t_kernel<<<dim3(D_MODEL/32,  D_INNER/32), 256, 0, stream>>>(Wout,Woutt,D_INNER, D_MODEL);
  wxcvt_kernel<<<D_INNER/256, 256, 0, stream>>>(Wx, Wxt);

  ln_kernel<<<NROWS, 256, 0, stream>>>(x, lng, lnb, xn);

  {
    const int gx = 2*D_INNER/128, gy = NROWS/128;   // 32 x 64 = 2048 blocks
    gemm_bk32<0><<<gx*gy, 256, 0, stream>>>(
        xn, W1t, nullptr, nullptr, (void*)xz, NROWS, 2*D_INNER, D_MODEL, gx, gy);
  }

  conv_silu_kernel<<<(NROWS*D_INNER/8)/256, 256, 0, stream>>>(xz, cw, cb, uu);

  xproj_kernel<<<NROWS/4, 256, 0, stream>>>(uu, Wxt, Bm);

  {
    const int gx = D_INNER/128, gy = NROWS/128;     // 16 x 64 = 1024 blocks
    gemm_bk32<1><<<gx*gy, 256, 0, stream>>>(
        uu, Wdtt, dtb, nullptr, (void*)dlt, NROWS, D_INNER, D_INNER, gx, gy);
  }

  scan_partial<<<dim3(D_INNER/256, BATCH, NCHUNK), 256, 0, stream>>>(
      uu, dlt, Bm, Alog, hend, sumdt);
  scan_combine<<<dim3(D_INNER/256, BATCH), 256, 0, stream>>>(
      hend, sumdt, Alog, hin);
  scan_final<<<dim3(D_INNER/256, BATCH, NCHUNK), 256, 0, stream>>>(
      uu, dlt, Bm, xz, Alog, Dpar, hin, yg);

  {
    const int gx = D_MODEL/128, gy = NROWS/128;     // 8 x 64 = 512 blocks
    gemm_bk32<2><<<gx*gy, 256, 0, stream>>>(
        yg, Woutt, nullptr, x, d_out, NROWS, D_MODEL, D_INNER, gx, gy);
  }

  (void)in_sizes; (void)n_in; (void)out_size; (void)ws_size;
}

// Round 5
// 763.493 us; speedup vs baseline: 1.2761x; 1.0441x over previous
//
#include <hip/hip_runtime.h>

typedef unsigned short u16;
typedef unsigned int   u32;

#define D_MODEL 1024
#define D_INNER 2048
#define D_STATE 16
#define SEQLEN  2048
#define BATCH   4
#define NROWS   (BATCH*SEQLEN)   // 8192
#define CHUNK   128
#define NCHUNK  (SEQLEN/CHUNK)   // 16

__device__ __forceinline__ float b2f(u16 v){
  union { u32 i; float f; } u; u.i = ((u32)v) << 16; return u.f;
}
__device__ __forceinline__ u16 f2b(float f){
  union { float f; u32 i; } u; u.f = f;
  u32 x = u.i;
  return (u16)((x + 0x7fffu + ((x >> 16) & 1u)) >> 16);  // RNE
}
__device__ __forceinline__ float h2f(u16 v){
  _Float16 h; __builtin_memcpy(&h, &v, 2); return (float)h;
}
__device__ __forceinline__ u16 f2h(float f){
  _Float16 h = (_Float16)f; u16 v; __builtin_memcpy(&v, &h, 2); return v;
}

typedef __bf16 bf16x8 __attribute__((ext_vector_type(8)));
typedef float  f32x4  __attribute__((ext_vector_type(4)));

// async global->LDS, 16B per lane; data for lane i lands at lds + i*16B.
__device__ __forceinline__ void async16(u16* lds, const u16* g){
  __builtin_amdgcn_global_load_lds(
      (const __attribute__((address_space(1))) void*)g,
      (__attribute__((address_space(3))) void*)lds,
      16, 0, 0);
}

// ---------------------------------------------------------------------------
// fp32 [Kd][Nd] -> bf16 transposed [Nd][Kd]   (32x32 LDS tiles)
// ---------------------------------------------------------------------------
__global__ __launch_bounds__(256) void wcvt_t_kernel(
    const float* __restrict__ W, u16* __restrict__ Bt, int Kd, int Nd)
{
  __shared__ u16 tile[32][33];
  const int n0 = blockIdx.x*32, k0 = blockIdx.y*32;
  const int tx = threadIdx.x & 31, ty = threadIdx.x >> 5;  // ty 0..7
  #pragma unroll
  for (int i=0;i<32;i+=8)
    tile[ty+i][tx] = f2b(W[(size_t)(k0+ty+i)*Nd + n0+tx]);   // tile[k][n]
  __syncthreads();
  #pragma unroll
  for (int i=0;i<32;i+=8)
    Bt[(size_t)(n0+ty+i)*Kd + k0+tx] = tile[tx][ty+i];
}

// Wx [2048][32] cols 16..31 -> Wxt bf16 [16][2048]
__global__ __launch_bounds__(256) void wxcvt_kernel(
    const float* __restrict__ Wx, u16* __restrict__ Wxt)
{
  const int k = blockIdx.x*256 + threadIdx.x;   // 0..2047
  #pragma unroll
  for (int n=0;n<16;n++)
    Wxt[n*D_INNER + k] = f2b(Wx[(size_t)k*32 + 16 + n]);
}

// ---------------------------------------------------------------------------
// Fused LayerNorm: x[row][1024] fp32 -> xn bf16
// ---------------------------------------------------------------------------
__global__ __launch_bounds__(256) void ln_kernel(
    const float* __restrict__ x, const float* __restrict__ g,
    const float* __restrict__ be, u16* __restrict__ xn)
{
  const int row = blockIdx.x;
  const float* xr = x + (size_t)row * D_MODEL;
  const int tid = threadIdx.x;
  float v[4]; float s = 0.f, s2 = 0.f;
  #pragma unroll
  for (int j=0;j<4;j++){
    float f = xr[tid + 256*j];
    v[j] = f; s += f; s2 += f*f;
  }
  #pragma unroll
  for (int o=32;o>0;o>>=1){ s += __shfl_down(s,o); s2 += __shfl_down(s2,o); }
  __shared__ float sh[8];
  const int wave = tid>>6, lane = tid&63;
  if (lane==0){ sh[wave]=s; sh[4+wave]=s2; }
  __syncthreads();
  const float ts  = sh[0]+sh[1]+sh[2]+sh[3];
  const float ts2 = sh[4]+sh[5]+sh[6]+sh[7];
  const float mu  = ts * (1.f/D_MODEL);
  const float var = ts2 * (1.f/D_MODEL) - mu*mu;
  const float rstd = rsqrtf(var + 1e-5f);
  u16* xo = xn + (size_t)row * D_MODEL;
  #pragma unroll
  for (int j=0;j<4;j++){
    int i = tid + 256*j;
    xo[i] = f2b((v[j]-mu)*rstd * g[i] + be[i]);
  }
}

// ---------------------------------------------------------------------------
// 128x128 MFMA GEMM, BK=32, forced 4-blocks/CU occupancy.
// Register-residency law (R0-R4 data): per-wave reg alloc rounds UP to a
// power of 2 (64/128/256); waves/CU = 2048/rounded.  acc[4][4] = 64 AGPR,
// so VGPR must be <=64 for the 128-reg class -> __launch_bounds__(256,4)
// forces the allocator there; inner loop restructured for low fragment
// liveness (bfr[4]=16 regs resident, one A fragment at a time).
// Stream law: MfmaUtil ~= S * 6.5 B/cyc * (FLOP/B=64) / 3377 -> ~49% at S=4.
// Swizzle: 16B-granule XOR (verified 0-conflict): pre-swizzled global source
// (linear global_load_lds dest), swizzled ds_read on the read side.
// A [M][K] bf16 ; Bt [N][K] bf16 (pre-transposed). 4 waves, 64x64 per wave.
// EPI 0: bf16 ; EPI 1: softplus(v+bias)->fp16 ; EPI 2: v+resid->fp32
// ---------------------------------------------------------------------------
template<int EPI>
__global__ __launch_bounds__(256, 4) void gemm_bk32(
    const u16* __restrict__ A, const u16* __restrict__ Bt,
    const float* __restrict__ bias, const float* __restrict__ resid,
    void* __restrict__ outv, int M, int N, int K, int gx, int gy)
{
  __shared__ __align__(16) u16 As[128*32];   // 8 KB
  __shared__ __align__(16) u16 Bs[128*32];   // 8 KB
  const int tid  = threadIdx.x;
  const int wave = tid >> 6, lane = tid & 63;
  const int quad = lane >> 4, l16 = lane & 15;

  // XCD swizzle: consecutive blocks on one XCD share the same n-column.
  const int lid = blockIdx.x;
  const int xcd = lid & 7, q = lid >> 3;
  const int cpx = gx >> 3;
  const int qd  = q / gy;
  const int bx  = xcd*cpx + qd;
  const int by  = q - qd*gy;
  const int m0 = by*128, n0 = bx*128;
  const int wm = (wave & 1)*64, wn = (wave >> 1)*64;

  // staging: wave covers rows wave*32..+31 of both tiles
  const int srow = wave*32 + (lane >> 2);
  const int gcol = ((lane & 3) ^ ((lane >> 3) & 3)) * 8;  // swizzled granule
  const u16* pA = A  + (size_t)(m0 + srow)*K + gcol;
  const u16* pB = Bt + (size_t)(n0 + srow)*K + gcol;
  u16* lA = &As[(wave*32)*32];
  u16* lB = &Bs[(wave*32)*32];

  // fragment LDS byte offsets
  const int sw   = quad ^ ((l16 >> 1) & 3);
  const int aoff = (wm + l16)*64 + sw*16;   // + mf*1024
  const int boff = (wn + l16)*64 + sw*16;   // + nf*1024

  f32x4 acc[4][4];
  #pragma unroll
  for (int i=0;i<4;i++)
    #pragma unroll
    for (int j=0;j<4;j++) acc[i][j] = (f32x4){0.f,0.f,0.f,0.f};

  #pragma unroll 1
  for (int k0 = 0; k0 < K; k0 += 32) {
    __syncthreads();                       // prev fragments consumed
    async16(lA,          pA + k0);
    async16(lA + 16*32,  pA + (size_t)16*K + k0);
    async16(lB,          pB + k0);
    async16(lB + 16*32,  pB + (size_t)16*K + k0);
    __syncthreads();                       // staging drained

    bf16x8 bfr[4];
    #pragma unroll
    for (int nf=0; nf<4; nf++)
      bfr[nf] = *reinterpret_cast<const bf16x8*>((const char*)Bs + boff + nf*1024);
    #pragma unroll
    for (int mf=0; mf<4; mf++){
      bf16x8 af = *reinterpret_cast<const bf16x8*>((const char*)As + aoff + mf*1024);
      #pragma unroll
      for (int nf=0; nf<4; nf++)
        acc[mf][nf] = __builtin_amdgcn_mfma_f32_16x16x32_bf16(af, bfr[nf], acc[mf][nf], 0, 0, 0);
    }
  }

  #pragma unroll
  for (int mf=0; mf<4; mf++){
    #pragma unroll
    for (int nf=0; nf<4; nf++){
      const int col = n0 + wn + nf*16 + l16;
      #pragma unroll
      for (int j=0;j<4;j++){
        const int row = m0 + wm + mf*16 + quad*4 + j;
        float v = acc[mf][nf][j];
        if (EPI == 1) {
          v += bias[col];
          v = (v > 20.f) ? v : log1pf(__expf(v));
          ((u16*)outv)[(size_t)row*N + col] = f2h(v);       // delta fp16
        } else if (EPI == 2) {
          v += resid[(size_t)row*N + col];
          ((float*)outv)[(size_t)row*N + col] = v;          // final out fp32
        } else {
          ((u16*)outv)[(size_t)row*N + col] = f2b(v);       // bf16 activation
        }
      }
    }
  }
}

// ---------------------------------------------------------------------------
// Causal depthwise conv(width 4) + bias + SiLU, 8 channels/thread vectorized.
// ---------------------------------------------------------------------------
__global__ __launch_bounds__(256) void conv_silu_kernel(
    const u16* __restrict__ xz, const float* __restrict__ cw,
    const float* __restrict__ cb, u16* __restrict__ u)
{
  const int idx = blockIdx.x*256 + threadIdx.x;   // (bt, c-group)
  const int c0 = (idx & 255) * 8;
  const int bt = idx >> 8;
  const int t  = bt & (SEQLEN-1);
  float acc[8];
  #pragma unroll
  for (int j=0;j<8;j++) acc[j] = cb[c0+j];
  #pragma unroll
  for (int k=0;k<4;k++){
    if (t - 3 + k >= 0){
      bf16x8 xv = *reinterpret_cast<const bf16x8*>(xz + (size_t)(bt-3+k)*4096 + c0);
      #pragma unroll
      for (int j=0;j<8;j++)
        acc[j] = fmaf(cw[(c0+j)*4 + k], (float)xv[j], acc[j]);
    }
  }
  u16 o[8];
  #pragma unroll
  for (int j=0;j<8;j++){
    float sv = acc[j] / (1.f + __expf(-acc[j]));
    o[j] = f2b(sv);
  }
  __builtin_memcpy(u + (size_t)bt*D_INNER + c0, o, 16);
}

// ---------------------------------------------------------------------------
// x_proj (cols 16..31 only): one wave per row, lane=(kq,n), bf16x8 both streams.
// ---------------------------------------------------------------------------
__global__ __launch_bounds__(256) void xproj_kernel(
    const u16* __restrict__ u, const u16* __restrict__ Wxt, float* __restrict__ Bm)
{
  const int wave = threadIdx.x >> 6, lane = threadIdx.x & 63;
  const int m = blockIdx.x*4 + wave;
  const int n = lane & 15, kq = lane >> 4;
  const u16* ur = u   + (size_t)m*D_INNER + kq*512;
  const u16* wr = Wxt + (size_t)n*D_INNER + kq*512;
  float acc = 0.f;
  #pragma unroll 4
  for (int i=0;i<512;i+=8){
    bf16x8 uv = *reinterpret_cast<const bf16x8*>(ur + i);
    bf16x8 wv = *reinterpret_cast<const bf16x8*>(wr + i);
    #pragma unroll
    for (int j=0;j<8;j++) acc = fmaf((float)uv[j], (float)wv[j], acc);
  }
  acc += __shfl_xor(acc, 16);
  acc += __shfl_xor(acc, 32);
  if (lane < 16) Bm[(size_t)m*16 + n] = acc;
}

// ---------------------------------------------------------------------------
// Chunked selective scan, 3 passes (exact linear-recurrence decomposition).
// ---------------------------------------------------------------------------
__global__ __launch_bounds__(256) void scan_partial(
    const u16* __restrict__ uu, const u16* __restrict__ delta16,
    const float* __restrict__ Bm, const float* __restrict__ Alog,
    float* __restrict__ hend, float* __restrict__ sumdt)
{
  const int b = blockIdx.y, ch = blockIdx.z;
  const int c = blockIdx.x*256 + threadIdx.x;
  const int row0 = b*SEQLEN + ch*CHUNK;
  float A[16], h[16];
  #pragma unroll
  for (int s=0;s<16;s++){ A[s] = -__expf(Alog[c*16+s]); h[s]=0.f; }
  __shared__ float Bsh[CHUNK*16];
  const float* src = Bm + (size_t)row0*16;
  #pragma unroll
  for (int j=0;j<8;j++) Bsh[threadIdx.x + 256*j] = src[threadIdx.x + 256*j];
  __syncthreads();

  float S = 0.f;
  float dta[8], uva[8], dtb[8], uvb[8];
  #pragma unroll
  for (int j=0;j<8;j++){
    size_t r = (size_t)(row0+j);
    dta[j] = h2f(delta16[r*D_INNER+c]);
    uva[j] = b2f(uu[r*D_INNER+c]);
  }
  #pragma unroll 1
  for (int g=0; g<CHUNK; g+=16){
    #pragma unroll
    for (int j=0;j<8;j++){
      int tl = g+8+j; tl = tl < CHUNK ? tl : CHUNK-1;
      size_t r = (size_t)(row0+tl);
      dtb[j] = h2f(delta16[r*D_INNER+c]);
      uvb[j] = b2f(uu[r*D_INNER+c]);
    }
    #pragma unroll
    for (int j=0;j<8;j++){
      float dt=dta[j], uv=uva[j]; S += dt; float xv=dt*uv;
      const float* Bt = &Bsh[(g+j)*16];
      #pragma unroll
      for (int s=0;s<16;s++) h[s] = fmaf(h[s], __expf(dt*A[s]), xv*Bt[s]);
    }
    #pragma unroll
    for (int j=0;j<8;j++){
      int tl = g+16+j; tl = tl < CHUNK ? tl : CHUNK-1;
      size_t r = (size_t)(row0+tl);
      dta[j] = h2f(delta16[r*D_INNER+c]);
      uva[j] = b2f(uu[r*D_INNER+c]);
    }
    #pragma unroll
    for (int j=0;j<8;j++){
      float dt=dtb[j], uv=uvb[j]; S += dt; float xv=dt*uv;
      const float* Bt = &Bsh[(g+8+j)*16];
      #pragma unroll
      for (int s=0;s<16;s++) h[s] = fmaf(h[s], __expf(dt*A[s]), xv*Bt[s]);
    }
  }
  const size_t base = ((size_t)(b*NCHUNK+ch)*16)*D_INNER + c;
  #pragma unroll
  for (int s=0;s<16;s++) hend[base + (size_t)s*D_INNER] = h[s];
  sumdt[(size_t)(b*NCHUNK+ch)*D_INNER + c] = S;
}

__global__ __launch_bounds__(256) void scan_combine(
    const float* __restrict__ hend, const float* __restrict__ sumdt,
    const float* __restrict__ Alog, float* __restrict__ hin)
{
  const int b = blockIdx.y;
  const int c = blockIdx.x*256 + threadIdx.x;
  float A[16], h[16];
  #pragma unroll
  for (int s=0;s<16;s++){ A[s] = -__expf(Alog[c*16+s]); h[s]=0.f; }
  #pragma unroll 1
  for (int k=0;k<NCHUNK;k++){
    const size_t base = ((size_t)(b*NCHUNK+k)*16)*D_INNER + c;
    #pragma unroll
    for (int s=0;s<16;s++) hin[base + (size_t)s*D_INNER] = h[s];
    const float S = sumdt[(size_t)(b*NCHUNK+k)*D_INNER + c];
    #pragma unroll
    for (int s=0;s<16;s++)
      h[s] = fmaf(h[s], __expf(S*A[s]), hend[base + (size_t)s*D_INNER]);
  }
}

__global__ __launch_bounds__(256) void scan_final(
    const u16* __restrict__ uu, const u16* __restrict__ delta16,
    const float* __restrict__ Bm, const u16* __restrict__ xz,
    const float* __restrict__ Alog, const float* __restrict__ Dpar,
    const float* __restrict__ hin, u16* __restrict__ yg)
{
  const int b = blockIdx.y, ch = blockIdx.z;
  const int c = blockIdx.x*256 + threadIdx.x;
  const int row0 = b*SEQLEN + ch*CHUNK;
  float A[16], h[16];
  const size_t base = ((size_t)(b*NCHUNK+ch)*16)*D_INNER + c;
  #pragma unroll
  for (int s=0;s<16;s++){
    A[s] = -__expf(Alog[c*16+s]);
    h[s] = hin[base + (size_t)s*D_INNER];
  }
  const float Dc = Dpar[c];
  __shared__ float Bsh[CHUNK*16];
  const float* src = Bm + (size_t)row0*16;
  #pragma unroll
  for (int j=0;j<8;j++) Bsh[threadIdx.x + 256*j] = src[threadIdx.x + 256*j];
  __syncthreads();

  float dta[8], uva[8], zva[8], dtb[8], uvb[8], zvb[8];
  #pragma unroll
  for (int j=0;j<8;j++){
    size_t r = (size_t)(row0+j);
    dta[j] = h2f(delta16[r*D_INNER+c]);
    uva[j] = b2f(uu[r*D_INNER+c]);
    zva[j] = b2f(xz[r*4096 + D_INNER + c]);
  }
  #pragma unroll 1
  for (int g=0; g<CHUNK; g+=16){
    #pragma unroll
    for (int j=0;j<8;j++){
      int tl = g+8+j; tl = tl < CHUNK ? tl : CHUNK-1;
      size_t r = (size_t)(row0+tl);
      dtb[j] = h2f(delta16[r*D_INNER+c]);
      uvb[j] = b2f(uu[r*D_INNER+c]);
      zvb[j] = b2f(xz[r*4096 + D_INNER + c]);
    }
    #pragma unroll
    for (int j=0;j<8;j++){
      float dt=dta[j], uv=uva[j], zv=zva[j];
      float xv=dt*uv, y=0.f;
      const float* Bt = &Bsh[(g+j)*16];
      #pragma unroll
      for (int s=0;s<16;s++){
        h[s] = fmaf(h[s], __expf(dt*A[s]), xv*Bt[s]);
        y += h[s];
      }
      y = fmaf(uv, Dc, y);
      float gz = zv/(1.f+__expf(-zv));
      yg[(size_t)(row0+g+j)*D_INNER + c] = f2b(y*gz);
    }
    #pragma unroll
    for (int j=0;j<8;j++){
      int tl = g+16+j; tl = tl < CHUNK ? tl : CHUNK-1;
      size_t r = (size_t)(row0+tl);
      dta[j] = h2f(delta16[r*D_INNER+c]);
      uva[j] = b2f(uu[r*D_INNER+c]);
      zva[j] = b2f(xz[r*4096 + D_INNER + c]);
    }
    #pragma unroll
    for (int j=0;j<8;j++){
      float dt=dtb[j], uv=uvb[j], zv=zvb[j];
      float xv=dt*uv, y=0.f;
      const float* Bt = &Bsh[(g+8+j)*16];
      #pragma unroll
      for (int s=0;s<16;s++){
        h[s] = fmaf(h[s], __expf(dt*A[s]), xv*Bt[s]);
        y += h[s];
      }
      y = fmaf(uv, Dc, y);
      float gz = zv/(1.f+__expf(-zv));
      yg[(size_t)(row0+g+8+j)*D_INNER + c] = f2b(y*gz);
    }
  }
}

// ---------------------------------------------------------------------------
extern "C" void kernel_launch(void* const* d_in, const int* in_sizes, int n_in,
                              void* d_out, int out_size, void* d_ws, size_t ws_size,
                              hipStream_t stream)
{
  const float* x    = (const float*)d_in[0];
  const float* lng  = (const float*)d_in[1];
  const float* lnb  = (const float*)d_in[2];
  const float* W1   = (const float*)d_in[3];
  const float* cw   = (const float*)d_in[4];
  const float* cb   = (const float*)d_in[5];
  const float* Wx   = (const float*)d_in[6];
  const float* Wdt  = (const float*)d_in[7];
  const float* dtb  = (const float*)d_in[8];
  const float* Alog = (const float*)d_in[9];
  const float* Dpar = (const float*)d_in[10];
  const float* Wout = (const float*)d_in[11];

  // workspace layout (MiB offsets), total ~199 MiB
  char* ws = (char*)d_ws;
  u16*   dlt   = (u16*)(ws);
  u16*   xn    = (u16*)(ws);                 // alias (sequenced)
  u16*   xz    = (u16*)(ws + (32llu<<20));
  u16*   uu    = (u16*)(ws + (96llu<<20));
  float* Bm    = (float*)(ws + (128llu<<20));
  u16*   W1t   = (u16*)(ws + (129llu<<20));
  u16*   Wdtt  = (u16*)(ws + (137llu<<20));
  u16*   Woutt = (u16*)(ws + (145llu<<20));
  u16*   yg    = (u16*)(ws + (149llu<<20));
  float* hend  = (float*)(ws + (181llu<<20));
  float* sumdt = (float*)(ws + (189llu<<20));
  float* hin   = (float*)(ws + (190llu<<20));
  u16*   Wxt   = (u16*)(ws + (198llu<<20));

  // weights -> bf16, transposed to [N][K]
  wcvt_t_kernel<<<dim3(2*D_INNER/32, D_MODEL/32), 256, 0, stream>>>(W1,  W1t,  D_MODEL, 2*D_INNER);
  wcvt_t_kernel<<<dim3(D_INNER/32,  D_INNER/32), 256, 0, stream>>>(Wdt, Wdtt, D_INNER, D_INNER);
  wcvt_t_kernel<<<dim3(D_MODEL/32,  D_INNER/32), 256, 0, stream>>>(Wout,Woutt,D_INNER, D_MODEL);
  wxcvt_kernel<<<D_INNER/256, 256, 0, stream>>>(Wx, Wxt);

  ln_kernel<<<NROWS, 256, 0, stream>>>(x, lng, lnb, xn);

  {
    const int gx = 2*D_INNER/128, gy = NROWS/128;   // 32 x 64 = 2048 blocks
    gemm_bk32<0><<<gx*gy, 256, 0, stream>>>(
        xn, W1t, nullptr, nullptr, (void*)xz, NROWS, 2*D_INNER, D_MODEL, gx, gy);
  }

  conv_silu_kernel<<<(NROWS*D_INNER/8)/256, 256, 0, stream>>>(xz, cw, cb, uu);

  xproj_kernel<<<NROWS/4, 256, 0, stream>>>(uu, Wxt, Bm);

  {
    const int gx = D_INNER/128, gy = NROWS/128;     // 16 x 64 = 1024 blocks
    gemm_bk32<1><<<gx*gy, 256, 0, stream>>>(
        uu, Wdtt, dtb, nullptr, (void*)dlt, NROWS, D_INNER, D_INNER, gx, gy);
  }

  scan_partial<<<dim3(D_INNER/256, BATCH, NCHUNK), 256, 0, stream>>>(
      uu, dlt, Bm, Alog, hend, sumdt);
  scan_combine<<<dim3(D_INNER/256, BATCH), 256, 0, stream>>>(
      hend, sumdt, Alog, hin);
  scan_final<<<dim3(D_INNER/256, BATCH, NCHUNK), 256, 0, stream>>>(
      uu, dlt, Bm, xz, Alog, Dpar, hin, yg);

  {
    const int gx = D_MODEL/128, gy = NROWS/128;     // 8 x 64 = 512 blocks
    gemm_bk32<2><<<gx*gy, 256, 0, stream>>>(
        yg, Woutt, nullptr, x, d_out, NROWS, D_MODEL, D_INNER, gx, gy);
  }

  (void)in_sizes; (void)n_in; (void)out_size; (void)ws_size;
}

// Round 6
// 761.185 us; speedup vs baseline: 1.2800x; 1.0030x over previous
//
#include <hip/hip_runtime.h>

typedef unsigned short u16;
typedef unsigned int   u32;

#define D_MODEL 1024
#define D_INNER 2048
#define D_STATE 16
#define SEQLEN  2048
#define BATCH   4
#define NROWS   (BATCH*SEQLEN)   // 8192
#define CHUNK   128
#define NCHUNK  (SEQLEN/CHUNK)   // 16

__device__ __forceinline__ float b2f(u16 v){
  union { u32 i; float f; } u; u.i = ((u32)v) << 16; return u.f;
}
__device__ __forceinline__ u16 f2b(float f){
  union { float f; u32 i; } u; u.f = f;
  u32 x = u.i;
  return (u16)((x + 0x7fffu + ((x >> 16) & 1u)) >> 16);  // RNE
}
__device__ __forceinline__ float h2f(u16 v){
  _Float16 h; __builtin_memcpy(&h, &v, 2); return (float)h;
}
__device__ __forceinline__ u16 f2h(float f){
  _Float16 h = (_Float16)f; u16 v; __builtin_memcpy(&v, &h, 2); return v;
}

typedef __bf16 bf16x8 __attribute__((ext_vector_type(8)));
typedef float  f32x4  __attribute__((ext_vector_type(4)));

// async global->LDS, 16B per lane; data for lane i lands at lds + i*16B.
__device__ __forceinline__ void async16(u16* lds, const u16* g){
  __builtin_amdgcn_global_load_lds(
      (const __attribute__((address_space(1))) void*)g,
      (__attribute__((address_space(3))) void*)lds,
      16, 0, 0);
}

// ---------------------------------------------------------------------------
// fp32 [Kd][Nd] -> bf16 transposed [Nd][Kd]   (32x32 LDS tiles)
// ---------------------------------------------------------------------------
__global__ __launch_bounds__(256) void wcvt_t_kernel(
    const float* __restrict__ W, u16* __restrict__ Bt, int Kd, int Nd)
{
  __shared__ u16 tile[32][33];
  const int n0 = blockIdx.x*32, k0 = blockIdx.y*32;
  const int tx = threadIdx.x & 31, ty = threadIdx.x >> 5;  // ty 0..7
  #pragma unroll
  for (int i=0;i<32;i+=8)
    tile[ty+i][tx] = f2b(W[(size_t)(k0+ty+i)*Nd + n0+tx]);   // tile[k][n]
  __syncthreads();
  #pragma unroll
  for (int i=0;i<32;i+=8)
    Bt[(size_t)(n0+ty+i)*Kd + k0+tx] = tile[tx][ty+i];
}

// Wx [2048][32] cols 16..31 -> Wxt bf16 [16][2048]
__global__ __launch_bounds__(256) void wxcvt_kernel(
    const float* __restrict__ Wx, u16* __restrict__ Wxt)
{
  const int k = blockIdx.x*256 + threadIdx.x;   // 0..2047
  #pragma unroll
  for (int n=0;n<16;n++)
    Wxt[n*D_INNER + k] = f2b(Wx[(size_t)k*32 + 16 + n]);
}

// ---------------------------------------------------------------------------
// Fused LayerNorm: x[row][1024] fp32 -> xn bf16
// ---------------------------------------------------------------------------
__global__ __launch_bounds__(256) void ln_kernel(
    const float* __restrict__ x, const float* __restrict__ g,
    const float* __restrict__ be, u16* __restrict__ xn)
{
  const int row = blockIdx.x;
  const float* xr = x + (size_t)row * D_MODEL;
  const int tid = threadIdx.x;
  float v[4]; float s = 0.f, s2 = 0.f;
  #pragma unroll
  for (int j=0;j<4;j++){
    float f = xr[tid + 256*j];
    v[j] = f; s += f; s2 += f*f;
  }
  #pragma unroll
  for (int o=32;o>0;o>>=1){ s += __shfl_down(s,o); s2 += __shfl_down(s2,o); }
  __shared__ float sh[8];
  const int wave = tid>>6, lane = tid&63;
  if (lane==0){ sh[wave]=s; sh[4+wave]=s2; }
  __syncthreads();
  const float ts  = sh[0]+sh[1]+sh[2]+sh[3];
  const float ts2 = sh[4]+sh[5]+sh[6]+sh[7];
  const float mu  = ts * (1.f/D_MODEL);
  const float var = ts2 * (1.f/D_MODEL) - mu*mu;
  const float rstd = rsqrtf(var + 1e-5f);
  u16* xo = xn + (size_t)row * D_MODEL;
  #pragma unroll
  for (int j=0;j<4;j++){
    int i = tid + 256*j;
    xo[i] = f2b((v[j]-mu)*rstd * g[i] + be[i]);
  }
}

// ---------------------------------------------------------------------------
// 128x128 MFMA GEMM, BK=32, double-buffered SINGLE-barrier 2-phase loop
// (T3 "minimum 2-phase" recipe).  Per K-step: issue next tile's 16 KB of
// global_load_lds FIRST, then ds_read+MFMA the current buffer, then ONE
// __syncthreads() (its vmcnt/lgkm drain covers the prefetch residual).
// Prefetch latency hides under the current tile's compute instead of
// sitting exposed between two barriers (R5 structure: 21% MfmaUtil).
// Occupancy class preserved from R5: acc[4][4]=64 AGPR + VGPR<=64 via
// __launch_bounds__(256,4); LDS 32 KB (2 bufs) -> still 3+ blocks/CU.
// Swizzle: 16B-granule XOR (verified 0-conflict): pre-swizzled global
// source (linear global_load_lds dest), swizzled ds_read on the read side.
// A [M][K] bf16 ; Bt [N][K] bf16 (pre-transposed). 4 waves, 64x64 per wave.
// EPI 0: bf16 ; EPI 1: softplus(v+bias)->fp16 ; EPI 2: v+resid->fp32
// ---------------------------------------------------------------------------
template<int EPI>
__global__ __launch_bounds__(256, 4) void gemm_db2(
    const u16* __restrict__ A, const u16* __restrict__ Bt,
    const float* __restrict__ bias, const float* __restrict__ resid,
    void* __restrict__ outv, int M, int N, int K, int gx, int gy)
{
  __shared__ __align__(16) u16 As[2*128*32];   // 16 KB (2 bufs x 8 KB)
  __shared__ __align__(16) u16 Bs[2*128*32];   // 16 KB
  const int tid  = threadIdx.x;
  const int wave = tid >> 6, lane = tid & 63;
  const int quad = lane >> 4, l16 = lane & 15;

  // XCD swizzle: consecutive blocks on one XCD share the same n-column.
  const int lid = blockIdx.x;
  const int xcd = lid & 7, q = lid >> 3;
  const int cpx = gx >> 3;
  const int qd  = q / gy;
  const int bx  = xcd*cpx + qd;
  const int by  = q - qd*gy;
  const int m0 = by*128, n0 = bx*128;
  const int wm = (wave & 1)*64, wn = (wave >> 1)*64;

  // staging: wave covers rows wave*32..+31 of both tiles
  const int srow = wave*32 + (lane >> 2);
  const int gcol = ((lane & 3) ^ ((lane >> 3) & 3)) * 8;  // swizzled granule
  const u16* pA = A  + (size_t)(m0 + srow)*K + gcol;
  const u16* pB = Bt + (size_t)(n0 + srow)*K + gcol;
  u16* lA = &As[wave*1024];   // + buf*4096 elems; +512 for rows +16
  u16* lB = &Bs[wave*1024];

  // fragment LDS byte offsets (within one buffer)
  const int sw   = quad ^ ((l16 >> 1) & 3);
  const int aoff = (wm + l16)*64 + sw*16;   // + mf*1024
  const int boff = (wn + l16)*64 + sw*16;   // + nf*1024

  f32x4 acc[4][4];
  #pragma unroll
  for (int i=0;i<4;i++)
    #pragma unroll
    for (int j=0;j<4;j++) acc[i][j] = (f32x4){0.f,0.f,0.f,0.f};

  // ---- prologue: stage tile 0 into buf 0 ----
  async16(lA,       pA);
  async16(lA + 512, pA + (size_t)16*K);
  async16(lB,       pB);
  async16(lB + 512, pB + (size_t)16*K);
  __syncthreads();                     // drains staging

  int cur = 0;
  #pragma unroll 1
  for (int k0 = 0; k0 < K; k0 += 32) {
    // ---- issue next tile's staging into the dead buffer FIRST ----
    const int kn = (k0 + 32 < K) ? k0 + 32 : k0;   // clamped tail (dead buf)
    const int nb = cur ^ 1;
    async16(lA + nb*4096,       pA + kn);
    async16(lA + nb*4096 + 512, pA + (size_t)16*K + kn);
    async16(lB + nb*4096,       pB + kn);
    async16(lB + nb*4096 + 512, pB + (size_t)16*K + kn);

    // ---- compute current buffer (hides prefetch latency) ----
    const char* aT = (const char*)As + cur*8192;
    const char* bT = (const char*)Bs + cur*8192;
    bf16x8 bfr[4];
    #pragma unroll
    for (int nf=0; nf<4; nf++)
      bfr[nf] = *reinterpret_cast<const bf16x8*>(bT + boff + nf*1024);
    #pragma unroll
    for (int mf=0; mf<4; mf++){
      bf16x8 af = *reinterpret_cast<const bf16x8*>(aT + aoff + mf*1024);
      #pragma unroll
      for (int nf=0; nf<4; nf++)
        acc[mf][nf] = __builtin_amdgcn_mfma_f32_16x16x32_bf16(af, bfr[nf], acc[mf][nf], 0, 0, 0);
    }

    __syncthreads();   // single sync point: drains prefetch residual + publishes
    cur = nb;
  }

  // ---- epilogue ----
  #pragma unroll
  for (int mf=0; mf<4; mf++){
    #pragma unroll
    for (int nf=0; nf<4; nf++){
      const int col = n0 + wn + nf*16 + l16;
      #pragma unroll
      for (int j=0;j<4;j++){
        const int row = m0 + wm + mf*16 + quad*4 + j;
        float v = acc[mf][nf][j];
        if (EPI == 1) {
          v += bias[col];
          v = (v > 20.f) ? v : log1pf(__expf(v));
          ((u16*)outv)[(size_t)row*N + col] = f2h(v);       // delta fp16
        } else if (EPI == 2) {
          v += resid[(size_t)row*N + col];
          ((float*)outv)[(size_t)row*N + col] = v;          // final out fp32
        } else {
          ((u16*)outv)[(size_t)row*N + col] = f2b(v);       // bf16 activation
        }
      }
    }
  }
}

// ---------------------------------------------------------------------------
// Causal depthwise conv(width 4) + bias + SiLU, 8 channels/thread vectorized.
// ---------------------------------------------------------------------------
__global__ __launch_bounds__(256) void conv_silu_kernel(
    const u16* __restrict__ xz, const float* __restrict__ cw,
    const float* __restrict__ cb, u16* __restrict__ u)
{
  const int idx = blockIdx.x*256 + threadIdx.x;   // (bt, c-group)
  const int c0 = (idx & 255) * 8;
  const int bt = idx >> 8;
  const int t  = bt & (SEQLEN-1);
  float acc[8];
  #pragma unroll
  for (int j=0;j<8;j++) acc[j] = cb[c0+j];
  #pragma unroll
  for (int k=0;k<4;k++){
    if (t - 3 + k >= 0){
      bf16x8 xv = *reinterpret_cast<const bf16x8*>(xz + (size_t)(bt-3+k)*4096 + c0);
      #pragma unroll
      for (int j=0;j<8;j++)
        acc[j] = fmaf(cw[(c0+j)*4 + k], (float)xv[j], acc[j]);
    }
  }
  u16 o[8];
  #pragma unroll
  for (int j=0;j<8;j++){
    float sv = acc[j] / (1.f + __expf(-acc[j]));
    o[j] = f2b(sv);
  }
  __builtin_memcpy(u + (size_t)bt*D_INNER + c0, o, 16);
}

// ---------------------------------------------------------------------------
// x_proj (cols 16..31 only): one wave per row, lane=(kq,n), bf16x8 both streams.
// ---------------------------------------------------------------------------
__global__ __launch_bounds__(256) void xproj_kernel(
    const u16* __restrict__ u, const u16* __restrict__ Wxt, float* __restrict__ Bm)
{
  const int wave = threadIdx.x >> 6, lane = threadIdx.x & 63;
  const int m = blockIdx.x*4 + wave;
  const int n = lane & 15, kq = lane >> 4;
  const u16* ur = u   + (size_t)m*D_INNER + kq*512;
  const u16* wr = Wxt + (size_t)n*D_INNER + kq*512;
  float acc = 0.f;
  #pragma unroll 4
  for (int i=0;i<512;i+=8){
    bf16x8 uv = *reinterpret_cast<const bf16x8*>(ur + i);
    bf16x8 wv = *reinterpret_cast<const bf16x8*>(wr + i);
    #pragma unroll
    for (int j=0;j<8;j++) acc = fmaf((float)uv[j], (float)wv[j], acc);
  }
  acc += __shfl_xor(acc, 16);
  acc += __shfl_xor(acc, 32);
  if (lane < 16) Bm[(size_t)m*16 + n] = acc;
}

// ---------------------------------------------------------------------------
// Chunked selective scan, 3 passes (exact linear-recurrence decomposition).
// ---------------------------------------------------------------------------
__global__ __launch_bounds__(256) void scan_partial(
    const u16* __restrict__ uu, const u16* __restrict__ delta16,
    const float* __restrict__ Bm, const float* __restrict__ Alog,
    float* __restrict__ hend, float* __restrict__ sumdt)
{
  const int b = blockIdx.y, ch = blockIdx.z;
  const int c = blockIdx.x*256 + threadIdx.x;
  const int row0 = b*SEQLEN + ch*CHUNK;
  float A[16], h[16];
  #pragma unroll
  for (int s=0;s<16;s++){ A[s] = -__expf(Alog[c*16+s]); h[s]=0.f; }
  __shared__ float Bsh[CHUNK*16];
  const float* src = Bm + (size_t)row0*16;
  #pragma unroll
  for (int j=0;j<8;j++) Bsh[threadIdx.x + 256*j] = src[threadIdx.x + 256*j];
  __syncthreads();

  float S = 0.f;
  float dta[8], uva[8], dtb[8], uvb[8];
  #pragma unroll
  for (int j=0;j<8;j++){
    size_t r = (size_t)(row0+j);
    dta[j] = h2f(delta16[r*D_INNER+c]);
    uva[j] = b2f(uu[r*D_INNER+c]);
  }
  #pragma unroll 1
  for (int g=0; g<CHUNK; g+=16){
    #pragma unroll
    for (int j=0;j<8;j++){
      int tl = g+8+j; tl = tl < CHUNK ? tl : CHUNK-1;
      size_t r = (size_t)(row0+tl);
      dtb[j] = h2f(delta16[r*D_INNER+c]);
      uvb[j] = b2f(uu[r*D_INNER+c]);
    }
    #pragma unroll
    for (int j=0;j<8;j++){
      float dt=dta[j], uv=uva[j]; S += dt; float xv=dt*uv;
      const float* Bt = &Bsh[(g+j)*16];
      #pragma unroll
      for (int s=0;s<16;s++) h[s] = fmaf(h[s], __expf(dt*A[s]), xv*Bt[s]);
    }
    #pragma unroll
    for (int j=0;j<8;j++){
      int tl = g+16+j; tl = tl < CHUNK ? tl : CHUNK-1;
      size_t r = (size_t)(row0+tl);
      dta[j] = h2f(delta16[r*D_INNER+c]);
      uva[j] = b2f(uu[r*D_INNER+c]);
    }
    #pragma unroll
    for (int j=0;j<8;j++){
      float dt=dtb[j], uv=uvb[j]; S += dt; float xv=dt*uv;
      const float* Bt = &Bsh[(g+8+j)*16];
      #pragma unroll
      for (int s=0;s<16;s++) h[s] = fmaf(h[s], __expf(dt*A[s]), xv*Bt[s]);
    }
  }
  const size_t base = ((size_t)(b*NCHUNK+ch)*16)*D_INNER + c;
  #pragma unroll
  for (int s=0;s<16;s++) hend[base + (size_t)s*D_INNER] = h[s];
  sumdt[(size_t)(b*NCHUNK+ch)*D_INNER + c] = S;
}

__global__ __launch_bounds__(256) void scan_combine(
    const float* __restrict__ hend, const float* __restrict__ sumdt,
    const float* __restrict__ Alog, float* __restrict__ hin)
{
  const int b = blockIdx.y;
  const int c = blockIdx.x*256 + threadIdx.x;
  float A[16], h[16];
  #pragma unroll
  for (int s=0;s<16;s++){ A[s] = -__expf(Alog[c*16+s]); h[s]=0.f; }
  #pragma unroll 1
  for (int k=0;k<NCHUNK;k++){
    const size_t base = ((size_t)(b*NCHUNK+k)*16)*D_INNER + c;
    #pragma unroll
    for (int s=0;s<16;s++) hin[base + (size_t)s*D_INNER] = h[s];
    const float S = sumdt[(size_t)(b*NCHUNK+k)*D_INNER + c];
    #pragma unroll
    for (int s=0;s<16;s++)
      h[s] = fmaf(h[s], __expf(S*A[s]), hend[base + (size_t)s*D_INNER]);
  }
}

__global__ __launch_bounds__(256) void scan_final(
    const u16* __restrict__ uu, const u16* __restrict__ delta16,
    const float* __restrict__ Bm, const u16* __restrict__ xz,
    const float* __restrict__ Alog, const float* __restrict__ Dpar,
    const float* __restrict__ hin, u16* __restrict__ yg)
{
  const int b = blockIdx.y, ch = blockIdx.z;
  const int c = blockIdx.x*256 + threadIdx.x;
  const int row0 = b*SEQLEN + ch*CHUNK;
  float A[16], h[16];
  const size_t base = ((size_t)(b*NCHUNK+ch)*16)*D_INNER + c;
  #pragma unroll
  for (int s=0;s<16;s++){
    A[s] = -__expf(Alog[c*16+s]);
    h[s] = hin[base + (size_t)s*D_INNER];
  }
  const float Dc = Dpar[c];
  __shared__ float Bsh[CHUNK*16];
  const float* src = Bm + (size_t)row0*16;
  #pragma unroll
  for (int j=0;j<8;j++) Bsh[threadIdx.x + 256*j] = src[threadIdx.x + 256*j];
  __syncthreads();

  float dta[8], uva[8], zva[8], dtb[8], uvb[8], zvb[8];
  #pragma unroll
  for (int j=0;j<8;j++){
    size_t r = (size_t)(row0+j);
    dta[j] = h2f(delta16[r*D_INNER+c]);
    uva[j] = b2f(uu[r*D_INNER+c]);
    zva[j] = b2f(xz[r*4096 + D_INNER + c]);
  }
  #pragma unroll 1
  for (int g=0; g<CHUNK; g+=16){
    #pragma unroll
    for (int j=0;j<8;j++){
      int tl = g+8+j; tl = tl < CHUNK ? tl : CHUNK-1;
      size_t r = (size_t)(row0+tl);
      dtb[j] = h2f(delta16[r*D_INNER+c]);
      uvb[j] = b2f(uu[r*D_INNER+c]);
      zvb[j] = b2f(xz[r*4096 + D_INNER + c]);
    }
    #pragma unroll
    for (int j=0;j<8;j++){
      float dt=dta[j], uv=uva[j], zv=zva[j];
      float xv=dt*uv, y=0.f;
      const float* Bt = &Bsh[(g+j)*16];
      #pragma unroll
      for (int s=0;s<16;s++){
        h[s] = fmaf(h[s], __expf(dt*A[s]), xv*Bt[s]);
        y += h[s];
      }
      y = fmaf(uv, Dc, y);
      float gz = zv/(1.f+__expf(-zv));
      yg[(size_t)(row0+g+j)*D_INNER + c] = f2b(y*gz);
    }
    #pragma unroll
    for (int j=0;j<8;j++){
      int tl = g+16+j; tl = tl < CHUNK ? tl : CHUNK-1;
      size_t r = (size_t)(row0+tl);
      dta[j] = h2f(delta16[r*D_INNER+c]);
      uva[j] = b2f(uu[r*D_INNER+c]);
      zva[j] = b2f(xz[r*4096 + D_INNER + c]);
    }
    #pragma unroll
    for (int j=0;j<8;j++){
      float dt=dtb[j], uv=uvb[j], zv=zvb[j];
      float xv=dt*uv, y=0.f;
      const float* Bt = &Bsh[(g+8+j)*16];
      #pragma unroll
      for (int s=0;s<16;s++){
        h[s] = fmaf(h[s], __expf(dt*A[s]), xv*Bt[s]);
        y += h[s];
      }
      y = fmaf(uv, Dc, y);
      float gz = zv/(1.f+__expf(-zv));
      yg[(size_t)(row0+g+8+j)*D_INNER + c] = f2b(y*gz);
    }
  }
}

// ---------------------------------------------------------------------------
extern "C" void kernel_launch(void* const* d_in, const int* in_sizes, int n_in,
                              void* d_out, int out_size, void* d_ws, size_t ws_size,
                              hipStream_t stream)
{
  const float* x    = (const float*)d_in[0];
  const float* lng  = (const float*)d_in[1];
  const float* lnb  = (const float*)d_in[2];
  const float* W1   = (const float*)d_in[3];
  const float* cw   = (const float*)d_in[4];
  const float* cb   = (const float*)d_in[5];
  const float* Wx   = (const float*)d_in[6];
  const float* Wdt  = (const float*)d_in[7];
  const float* dtb  = (const float*)d_in[8];
  const float* Alog = (const float*)d_in[9];
  const float* Dpar = (const float*)d_in[10];
  const float* Wout = (const float*)d_in[11];

  // workspace layout (MiB offsets), total ~199 MiB
  char* ws = (char*)d_ws;
  u16*   dlt   = (u16*)(ws);
  u16*   xn    = (u16*)(ws);                 // alias (sequenced)
  u16*   xz    = (u16*)(ws + (32llu<<20));
  u16*   uu    = (u16*)(ws + (96llu<<20));
  float* Bm    = (float*)(ws + (128llu<<20));
  u16*   W1t   = (u16*)(ws + (129llu<<20));
  u16*   Wdtt  = (u16*)(ws + (137llu<<20));
  u16*   Woutt = (u16*)(ws + (145llu<<20));
  u16*   yg    = (u16*)(ws + (149llu<<20));
  float* hend  = (float*)(ws + (181llu<<20));
  float* sumdt = (float*)(ws + (189llu<<20));
  float* hin   = (float*)(ws + (190llu<<20));
  u16*   Wxt   = (u16*)(ws + (198llu<<20));

  // weights -> bf16, transposed to [N][K]
  wcvt_t_kernel<<<dim3(2*D_INNER/32, D_MODEL/32), 256, 0, stream>>>(W1,  W1t,  D_MODEL, 2*D_INNER);
  wcvt_t_kernel<<<dim3(D_INNER/32,  D_INNER/32), 256, 0, stream>>>(Wdt, Wdtt, D_INNER, D_INNER);
  wcvt_t_kernel<<<dim3(D_MODEL/32,  D_INNER/32), 256, 0, stream>>>(Wout,Woutt,D_INNER, D_MODEL);
  wxcvt_kernel<<<D_INNER/256, 256, 0, stream>>>(Wx, Wxt);

  ln_kernel<<<NROWS, 256, 0, stream>>>(x, lng, lnb, xn);

  {
    const int gx = 2*D_INNER/128, gy = NROWS/128;   // 32 x 64 = 2048 blocks
    gemm_db2<0><<<gx*gy, 256, 0, stream>>>(
        xn, W1t, nullptr, nullptr, (void*)xz, NROWS, 2*D_INNER, D_MODEL, gx, gy);
  }

  conv_silu_kernel<<<(NROWS*D_INNER/8)/256, 256, 0, stream>>>(xz, cw, cb, uu);

  xproj_kernel<<<NROWS/4, 256, 0, stream>>>(uu, Wxt, Bm);

  {
    const int gx = D_INNER/128, gy = NROWS/128;     // 16 x 64 = 1024 blocks
    gemm_db2<1><<<gx*gy, 256, 0, stream>>>(
        uu, Wdtt, dtb, nullptr, (void*)dlt, NROWS, D_INNER, D_INNER, gx, gy);
  }

  scan_partial<<<dim3(D_INNER/256, BATCH, NCHUNK), 256, 0, stream>>>(
      uu, dlt, Bm, Alog, hend, sumdt);
  scan_combine<<<dim3(D_INNER/256, BATCH), 256, 0, stream>>>(
      hend, sumdt, Alog, hin);
  scan_final<<<dim3(D_INNER/256, BATCH, NCHUNK), 256, 0, stream>>>(
      uu, dlt, Bm, xz, Alog, Dpar, hin, yg);

  {
    const int gx = D_MODEL/128, gy = NROWS/128;     // 8 x 64 = 512 blocks
    gemm_db2<2><<<gx*gy, 256, 0, stream>>>(
        yg, Woutt, nullptr, x, d_out, NROWS, D_MODEL, D_INNER, gx, gy);
  }

  (void)in_sizes; (void)n_in; (void)out_size; (void)ws_size;
}

// Round 7
// 696.787 us; speedup vs baseline: 1.3983x; 1.0924x over previous
//
#include <hip/hip_runtime.h>

typedef unsigned short u16;
typedef unsigned int   u32;

#define D_MODEL 1024
#define D_INNER 2048
#define D_STATE 16
#define SEQLEN  2048
#define BATCH   4
#define NROWS   (BATCH*SEQLEN)   // 8192
#define CHUNK   128
#define NCHUNK  (SEQLEN/CHUNK)   // 16

__device__ __forceinline__ float b2f(u16 v){
  union { u32 i; float f; } u; u.i = ((u32)v) << 16; return u.f;
}
__device__ __forceinline__ u16 f2b(float f){
  union { float f; u32 i; } u; u.f = f;
  u32 x = u.i;
  return (u16)((x + 0x7fffu + ((x >> 16) & 1u)) >> 16);  // RNE
}
__device__ __forceinline__ float h2f(u16 v){
  _Float16 h; __builtin_memcpy(&h, &v, 2); return (float)h;
}
__device__ __forceinline__ u16 f2h(float f){
  _Float16 h = (_Float16)f; u16 v; __builtin_memcpy(&v, &h, 2); return v;
}

typedef __bf16 bf16x8 __attribute__((ext_vector_type(8)));
typedef float  f32x4  __attribute__((ext_vector_type(4)));

// async global->LDS, 16B per lane; data for lane i lands at lds + i*16B.
__device__ __forceinline__ void async16(u16* lds, const u16* g){
  __builtin_amdgcn_global_load_lds(
      (const __attribute__((address_space(1))) void*)g,
      (__attribute__((address_space(3))) void*)lds,
      16, 0, 0);
}

// ---------------------------------------------------------------------------
// fp32 [Kd][Nd] -> bf16 transposed [Nd][Kd]   (32x32 LDS tiles)
// ---------------------------------------------------------------------------
__global__ __launch_bounds__(256) void wcvt_t_kernel(
    const float* __restrict__ W, u16* __restrict__ Bt, int Kd, int Nd)
{
  __shared__ u16 tile[32][33];
  const int n0 = blockIdx.x*32, k0 = blockIdx.y*32;
  const int tx = threadIdx.x & 31, ty = threadIdx.x >> 5;  // ty 0..7
  #pragma unroll
  for (int i=0;i<32;i+=8)
    tile[ty+i][tx] = f2b(W[(size_t)(k0+ty+i)*Nd + n0+tx]);   // tile[k][n]
  __syncthreads();
  #pragma unroll
  for (int i=0;i<32;i+=8)
    Bt[(size_t)(n0+ty+i)*Kd + k0+tx] = tile[tx][ty+i];
}

// Wx [2048][32] cols 16..31 -> Wxt bf16 [16][2048]
__global__ __launch_bounds__(256) void wxcvt_kernel(
    const float* __restrict__ Wx, u16* __restrict__ Wxt)
{
  const int k = blockIdx.x*256 + threadIdx.x;   // 0..2047
  #pragma unroll
  for (int n=0;n<16;n++)
    Wxt[n*D_INNER + k] = f2b(Wx[(size_t)k*32 + 16 + n]);
}

// ---------------------------------------------------------------------------
// Fused LayerNorm: x[row][1024] fp32 -> xn bf16
// ---------------------------------------------------------------------------
__global__ __launch_bounds__(256) void ln_kernel(
    const float* __restrict__ x, const float* __restrict__ g,
    const float* __restrict__ be, u16* __restrict__ xn)
{
  const int row = blockIdx.x;
  const float* xr = x + (size_t)row * D_MODEL;
  const int tid = threadIdx.x;
  float v[4]; float s = 0.f, s2 = 0.f;
  #pragma unroll
  for (int j=0;j<4;j++){
    float f = xr[tid + 256*j];
    v[j] = f; s += f; s2 += f*f;
  }
  #pragma unroll
  for (int o=32;o>0;o>>=1){ s += __shfl_down(s,o); s2 += __shfl_down(s2,o); }
  __shared__ float sh[8];
  const int wave = tid>>6, lane = tid&63;
  if (lane==0){ sh[wave]=s; sh[4+wave]=s2; }
  __syncthreads();
  const float ts  = sh[0]+sh[1]+sh[2]+sh[3];
  const float ts2 = sh[4]+sh[5]+sh[6]+sh[7];
  const float mu  = ts * (1.f/D_MODEL);
  const float var = ts2 * (1.f/D_MODEL) - mu*mu;
  const float rstd = rsqrtf(var + 1e-5f);
  u16* xo = xn + (size_t)row * D_MODEL;
  #pragma unroll
  for (int j=0;j<4;j++){
    int i = tid + 256*j;
    xo[i] = f2b((v[j]-mu)*rstd * g[i] + be[i]);
  }
}

// ---------------------------------------------------------------------------
// 128x128 MFMA GEMM, BK=32, double-buffered single-barrier loop (R6, kept
// unchanged: established operating point, MfmaUtil ~21%, ~3 blocks/CU).
// ---------------------------------------------------------------------------
template<int EPI>
__global__ __launch_bounds__(256, 4) void gemm_db2(
    const u16* __restrict__ A, const u16* __restrict__ Bt,
    const float* __restrict__ bias, const float* __restrict__ resid,
    void* __restrict__ outv, int M, int N, int K, int gx, int gy)
{
  __shared__ __align__(16) u16 As[2*128*32];   // 16 KB (2 bufs x 8 KB)
  __shared__ __align__(16) u16 Bs[2*128*32];   // 16 KB
  const int tid  = threadIdx.x;
  const int wave = tid >> 6, lane = tid & 63;
  const int quad = lane >> 4, l16 = lane & 15;

  // XCD swizzle: consecutive blocks on one XCD share the same n-column.
  const int lid = blockIdx.x;
  const int xcd = lid & 7, q = lid >> 3;
  const int cpx = gx >> 3;
  const int qd  = q / gy;
  const int bx  = xcd*cpx + qd;
  const int by  = q - qd*gy;
  const int m0 = by*128, n0 = bx*128;
  const int wm = (wave & 1)*64, wn = (wave >> 1)*64;

  // staging: wave covers rows wave*32..+31 of both tiles
  const int srow = wave*32 + (lane >> 2);
  const int gcol = ((lane & 3) ^ ((lane >> 3) & 3)) * 8;  // swizzled granule
  const u16* pA = A  + (size_t)(m0 + srow)*K + gcol;
  const u16* pB = Bt + (size_t)(n0 + srow)*K + gcol;
  u16* lA = &As[wave*1024];   // + buf*4096 elems; +512 for rows +16
  u16* lB = &Bs[wave*1024];

  // fragment LDS byte offsets (within one buffer)
  const int sw   = quad ^ ((l16 >> 1) & 3);
  const int aoff = (wm + l16)*64 + sw*16;   // + mf*1024
  const int boff = (wn + l16)*64 + sw*16;   // + nf*1024

  f32x4 acc[4][4];
  #pragma unroll
  for (int i=0;i<4;i++)
    #pragma unroll
    for (int j=0;j<4;j++) acc[i][j] = (f32x4){0.f,0.f,0.f,0.f};

  // ---- prologue: stage tile 0 into buf 0 ----
  async16(lA,       pA);
  async16(lA + 512, pA + (size_t)16*K);
  async16(lB,       pB);
  async16(lB + 512, pB + (size_t)16*K);
  __syncthreads();                     // drains staging

  int cur = 0;
  #pragma unroll 1
  for (int k0 = 0; k0 < K; k0 += 32) {
    // ---- issue next tile's staging into the dead buffer FIRST ----
    const int kn = (k0 + 32 < K) ? k0 + 32 : k0;   // clamped tail (dead buf)
    const int nb = cur ^ 1;
    async16(lA + nb*4096,       pA + kn);
    async16(lA + nb*4096 + 512, pA + (size_t)16*K + kn);
    async16(lB + nb*4096,       pB + kn);
    async16(lB + nb*4096 + 512, pB + (size_t)16*K + kn);

    // ---- compute current buffer ----
    const char* aT = (const char*)As + cur*8192;
    const char* bT = (const char*)Bs + cur*8192;
    bf16x8 bfr[4];
    #pragma unroll
    for (int nf=0; nf<4; nf++)
      bfr[nf] = *reinterpret_cast<const bf16x8*>(bT + boff + nf*1024);
    #pragma unroll
    for (int mf=0; mf<4; mf++){
      bf16x8 af = *reinterpret_cast<const bf16x8*>(aT + aoff + mf*1024);
      #pragma unroll
      for (int nf=0; nf<4; nf++)
        acc[mf][nf] = __builtin_amdgcn_mfma_f32_16x16x32_bf16(af, bfr[nf], acc[mf][nf], 0, 0, 0);
    }

    __syncthreads();   // single sync point: drains prefetch + publishes
    cur = nb;
  }

  // ---- epilogue ----
  #pragma unroll
  for (int mf=0; mf<4; mf++){
    #pragma unroll
    for (int nf=0; nf<4; nf++){
      const int col = n0 + wn + nf*16 + l16;
      #pragma unroll
      for (int j=0;j<4;j++){
        const int row = m0 + wm + mf*16 + quad*4 + j;
        float v = acc[mf][nf][j];
        if (EPI == 1) {
          v += bias[col];
          v = (v > 20.f) ? v : log1pf(__expf(v));
          ((u16*)outv)[(size_t)row*N + col] = f2h(v);       // delta fp16
        } else if (EPI == 2) {
          v += resid[(size_t)row*N + col];
          ((float*)outv)[(size_t)row*N + col] = v;          // final out fp32
        } else {
          ((u16*)outv)[(size_t)row*N + col] = f2b(v);       // bf16 activation
        }
      }
    }
  }
}

// ---------------------------------------------------------------------------
// FUSED: causal depthwise conv(4) + bias + SiLU  ->  u (bf16)  AND
// x_proj B-columns (cols 16..31): Bm[bt][n] = sum_c u[c]*Wxt[n][c].
// One block per bt row; the full 2048-channel u row lives in registers
// (8 ch/thread), so the 16 dot-products are computed in-register + wave
// shuffle-reduce — deletes the old xproj kernel and its 33.5 MB re-read
// of uu.  Uses pre-rounding fp32 u values (closer to fp32 reference).
// ---------------------------------------------------------------------------
__global__ __launch_bounds__(256) void conv_silu_xproj_kernel(
    const u16* __restrict__ xz, const float* __restrict__ cw,
    const float* __restrict__ cb, const u16* __restrict__ Wxt,
    u16* __restrict__ u, float* __restrict__ Bm)
{
  const int bt = blockIdx.x;            // 0..NROWS-1
  const int t  = bt & (SEQLEN-1);
  const int c0 = threadIdx.x * 8;
  float acc[8];
  #pragma unroll
  for (int j=0;j<8;j++) acc[j] = cb[c0+j];
  #pragma unroll
  for (int k=0;k<4;k++){
    if (t - 3 + k >= 0){
      bf16x8 xv = *reinterpret_cast<const bf16x8*>(xz + (size_t)(bt-3+k)*4096 + c0);
      #pragma unroll
      for (int j=0;j<8;j++)
        acc[j] = fmaf(cw[(c0+j)*4 + k], (float)xv[j], acc[j]);
    }
  }
  float sv[8]; u16 o[8];
  #pragma unroll
  for (int j=0;j<8;j++){
    sv[j] = acc[j] / (1.f + __expf(-acc[j]));
    o[j] = f2b(sv[j]);
  }
  __builtin_memcpy(u + (size_t)bt*D_INNER + c0, o, 16);

  // ---- x_proj partials: 16 dot-products over this thread's 8 channels ----
  float pn[16];
  #pragma unroll
  for (int n=0;n<16;n++){
    bf16x8 wv = *reinterpret_cast<const bf16x8*>(Wxt + (size_t)n*D_INNER + c0);
    float s = 0.f;
    #pragma unroll
    for (int j=0;j<8;j++) s = fmaf(sv[j], (float)wv[j], s);
    pn[n] = s;
  }
  // wave butterfly reduce each of the 16 partials
  #pragma unroll
  for (int n=0;n<16;n++){
    #pragma unroll
    for (int off=1; off<64; off<<=1) pn[n] += __shfl_xor(pn[n], off);
  }
  __shared__ float red[4][16];
  const int wave = threadIdx.x >> 6, lane = threadIdx.x & 63;
  if (lane == 0){
    #pragma unroll
    for (int n=0;n<16;n++) red[wave][n] = pn[n];
  }
  __syncthreads();
  if (threadIdx.x < 16){
    const int n = threadIdx.x;
    Bm[(size_t)bt*16 + n] = red[0][n]+red[1][n]+red[2][n]+red[3][n];
  }
}

// ---------------------------------------------------------------------------
// Chunked selective scan, 3 passes (exact linear-recurrence decomposition).
// ---------------------------------------------------------------------------
__global__ __launch_bounds__(256) void scan_partial(
    const u16* __restrict__ uu, const u16* __restrict__ delta16,
    const float* __restrict__ Bm, const float* __restrict__ Alog,
    float* __restrict__ hend, float* __restrict__ sumdt)
{
  const int b = blockIdx.y, ch = blockIdx.z;
  const int c = blockIdx.x*256 + threadIdx.x;
  const int row0 = b*SEQLEN + ch*CHUNK;
  float A[16], h[16];
  #pragma unroll
  for (int s=0;s<16;s++){ A[s] = -__expf(Alog[c*16+s]); h[s]=0.f; }
  __shared__ float Bsh[CHUNK*16];
  const float* src = Bm + (size_t)row0*16;
  #pragma unroll
  for (int j=0;j<8;j++) Bsh[threadIdx.x + 256*j] = src[threadIdx.x + 256*j];
  __syncthreads();

  float S = 0.f;
  float dta[8], uva[8], dtb[8], uvb[8];
  #pragma unroll
  for (int j=0;j<8;j++){
    size_t r = (size_t)(row0+j);
    dta[j] = h2f(delta16[r*D_INNER+c]);
    uva[j] = b2f(uu[r*D_INNER+c]);
  }
  #pragma unroll 1
  for (int g=0; g<CHUNK; g+=16){
    #pragma unroll
    for (int j=0;j<8;j++){
      int tl = g+8+j; tl = tl < CHUNK ? tl : CHUNK-1;
      size_t r = (size_t)(row0+tl);
      dtb[j] = h2f(delta16[r*D_INNER+c]);
      uvb[j] = b2f(uu[r*D_INNER+c]);
    }
    #pragma unroll
    for (int j=0;j<8;j++){
      float dt=dta[j], uv=uva[j]; S += dt; float xv=dt*uv;
      const float* Bt = &Bsh[(g+j)*16];
      #pragma unroll
      for (int s=0;s<16;s++) h[s] = fmaf(h[s], __expf(dt*A[s]), xv*Bt[s]);
    }
    #pragma unroll
    for (int j=0;j<8;j++){
      int tl = g+16+j; tl = tl < CHUNK ? tl : CHUNK-1;
      size_t r = (size_t)(row0+tl);
      dta[j] = h2f(delta16[r*D_INNER+c]);
      uva[j] = b2f(uu[r*D_INNER+c]);
    }
    #pragma unroll
    for (int j=0;j<8;j++){
      float dt=dtb[j], uv=uvb[j]; S += dt; float xv=dt*uv;
      const float* Bt = &Bsh[(g+8+j)*16];
      #pragma unroll
      for (int s=0;s<16;s++) h[s] = fmaf(h[s], __expf(dt*A[s]), xv*Bt[s]);
    }
  }
  const size_t base = ((size_t)(b*NCHUNK+ch)*16)*D_INNER + c;
  #pragma unroll
  for (int s=0;s<16;s++) hend[base + (size_t)s*D_INNER] = h[s];
  sumdt[(size_t)(b*NCHUNK+ch)*D_INNER + c] = S;
}

// Parallelized over (channel, state): 16x more threads than the old version
// (which ran 32 blocks = 12.5% of CUs, serial over independent states).
__global__ __launch_bounds__(256) void scan_combine(
    const float* __restrict__ hend, const float* __restrict__ sumdt,
    const float* __restrict__ Alog, float* __restrict__ hin)
{
  const int b = blockIdx.y;
  const int idx = blockIdx.x*256 + threadIdx.x;   // 0..D_INNER*16-1
  const int s = idx >> 11, c = idx & (D_INNER-1);
  const float A = -__expf(Alog[c*16+s]);
  float h = 0.f;
  #pragma unroll 1
  for (int k=0;k<NCHUNK;k++){
    const size_t base = (((size_t)(b*NCHUNK+k)*16)+s)*D_INNER + c;
    hin[base] = h;
    const float S = sumdt[(size_t)(b*NCHUNK+k)*D_INNER + c];
    h = fmaf(h, __expf(S*A), hend[base]);
  }
}

__global__ __launch_bounds__(256) void scan_final(
    const u16* __restrict__ uu, const u16* __restrict__ delta16,
    const float* __restrict__ Bm, const u16* __restrict__ xz,
    const float* __restrict__ Alog, const float* __restrict__ Dpar,
    const float* __restrict__ hin, u16* __restrict__ yg)
{
  const int b = blockIdx.y, ch = blockIdx.z;
  const int c = blockIdx.x*256 + threadIdx.x;
  const int row0 = b*SEQLEN + ch*CHUNK;
  float A[16], h[16];
  const size_t base = ((size_t)(b*NCHUNK+ch)*16)*D_INNER + c;
  #pragma unroll
  for (int s=0;s<16;s++){
    A[s] = -__expf(Alog[c*16+s]);
    h[s] = hin[base + (size_t)s*D_INNER];
  }
  const float Dc = Dpar[c];
  __shared__ float Bsh[CHUNK*16];
  const float* src = Bm + (size_t)row0*16;
  #pragma unroll
  for (int j=0;j<8;j++) Bsh[threadIdx.x + 256*j] = src[threadIdx.x + 256*j];
  __syncthreads();

  float dta[8], uva[8], zva[8], dtb[8], uvb[8], zvb[8];
  #pragma unroll
  for (int j=0;j<8;j++){
    size_t r = (size_t)(row0+j);
    dta[j] = h2f(delta16[r*D_INNER+c]);
    uva[j] = b2f(uu[r*D_INNER+c]);
    zva[j] = b2f(xz[r*4096 + D_INNER + c]);
  }
  #pragma unroll 1
  for (int g=0; g<CHUNK; g+=16){
    #pragma unroll
    for (int j=0;j<8;j++){
      int tl = g+8+j; tl = tl < CHUNK ? tl : CHUNK-1;
      size_t r = (size_t)(row0+tl);
      dtb[j] = h2f(delta16[r*D_INNER+c]);
      uvb[j] = b2f(uu[r*D_INNER+c]);
      zvb[j] = b2f(xz[r*4096 + D_INNER + c]);
    }
    #pragma unroll
    for (int j=0;j<8;j++){
      float dt=dta[j], uv=uva[j], zv=zva[j];
      float xv=dt*uv, y=0.f;
      const float* Bt = &Bsh[(g+j)*16];
      #pragma unroll
      for (int s=0;s<16;s++){
        h[s] = fmaf(h[s], __expf(dt*A[s]), xv*Bt[s]);
        y += h[s];
      }
      y = fmaf(uv, Dc, y);
      float gz = zv/(1.f+__expf(-zv));
      yg[(size_t)(row0+g+j)*D_INNER + c] = f2b(y*gz);
    }
    #pragma unroll
    for (int j=0;j<8;j++){
      int tl = g+16+j; tl = tl < CHUNK ? tl : CHUNK-1;
      size_t r = (size_t)(row0+tl);
      dta[j] = h2f(delta16[r*D_INNER+c]);
      uva[j] = b2f(uu[r*D_INNER+c]);
      zva[j] = b2f(xz[r*4096 + D_INNER + c]);
    }
    #pragma unroll
    for (int j=0;j<8;j++){
      float dt=dtb[j], uv=uvb[j], zv=zvb[j];
      float xv=dt*uv, y=0.f;
      const float* Bt = &Bsh[(g+8+j)*16];
      #pragma unroll
      for (int s=0;s<16;s++){
        h[s] = fmaf(h[s], __expf(dt*A[s]), xv*Bt[s]);
        y += h[s];
      }
      y = fmaf(uv, Dc, y);
      float gz = zv/(1.f+__expf(-zv));
      yg[(size_t)(row0+g+8+j)*D_INNER + c] = f2b(y*gz);
    }
  }
}

// ---------------------------------------------------------------------------
extern "C" void kernel_launch(void* const* d_in, const int* in_sizes, int n_in,
                              void* d_out, int out_size, void* d_ws, size_t ws_size,
                              hipStream_t stream)
{
  const float* x    = (const float*)d_in[0];
  const float* lng  = (const float*)d_in[1];
  const float* lnb  = (const float*)d_in[2];
  const float* W1   = (const float*)d_in[3];
  const float* cw   = (const float*)d_in[4];
  const float* cb   = (const float*)d_in[5];
  const float* Wx   = (const float*)d_in[6];
  const float* Wdt  = (const float*)d_in[7];
  const float* dtb  = (const float*)d_in[8];
  const float* Alog = (const float*)d_in[9];
  const float* Dpar = (const float*)d_in[10];
  const float* Wout = (const float*)d_in[11];

  // workspace layout (MiB offsets), total ~199 MiB
  char* ws = (char*)d_ws;
  u16*   dlt   = (u16*)(ws);
  u16*   xn    = (u16*)(ws);                 // alias (sequenced)
  u16*   xz    = (u16*)(ws + (32llu<<20));
  u16*   uu    = (u16*)(ws + (96llu<<20));
  float* Bm    = (float*)(ws + (128llu<<20));
  u16*   W1t   = (u16*)(ws + (129llu<<20));
  u16*   Wdtt  = (u16*)(ws + (137llu<<20));
  u16*   Woutt = (u16*)(ws + (145llu<<20));
  u16*   yg    = (u16*)(ws + (149llu<<20));
  float* hend  = (float*)(ws + (181llu<<20));
  float* sumdt = (float*)(ws + (189llu<<20));
  float* hin   = (float*)(ws + (190llu<<20));
  u16*   Wxt   = (u16*)(ws + (198llu<<20));

  // weights -> bf16, transposed to [N][K]
  wcvt_t_kernel<<<dim3(2*D_INNER/32, D_MODEL/32), 256, 0, stream>>>(W1,  W1t,  D_MODEL, 2*D_INNER);
  wcvt_t_kernel<<<dim3(D_INNER/32,  D_INNER/32), 256, 0, stream>>>(Wdt, Wdtt, D_INNER, D_INNER);
  wcvt_t_kernel<<<dim3(D_MODEL/32,  D_INNER/32), 256, 0, stream>>>(Wout,Woutt,D_INNER, D_MODEL);
  wxcvt_kernel<<<D_INNER/256, 256, 0, stream>>>(Wx, Wxt);

  ln_kernel<<<NROWS, 256, 0, stream>>>(x, lng, lnb, xn);

  {
    const int gx = 2*D_INNER/128, gy = NROWS/128;   // 32 x 64 = 2048 blocks
    gemm_db2<0><<<gx*gy, 256, 0, stream>>>(
        xn, W1t, nullptr, nullptr, (void*)xz, NROWS, 2*D_INNER, D_MODEL, gx, gy);
  }

  conv_silu_xproj_kernel<<<NROWS, 256, 0, stream>>>(xz, cw, cb, Wxt, uu, Bm);

  {
    const int gx = D_INNER/128, gy = NROWS/128;     // 16 x 64 = 1024 blocks
    gemm_db2<1><<<gx*gy, 256, 0, stream>>>(
        uu, Wdtt, dtb, nullptr, (void*)dlt, NROWS, D_INNER, D_INNER, gx, gy);
  }

  scan_partial<<<dim3(D_INNER/256, BATCH, NCHUNK), 256, 0, stream>>>(
      uu, dlt, Bm, Alog, hend, sumdt);
  scan_combine<<<dim3(D_INNER*16/256, BATCH), 256, 0, stream>>>(
      hend, sumdt, Alog, hin);
  scan_final<<<dim3(D_INNER/256, BATCH, NCHUNK), 256, 0, stream>>>(
      uu, dlt, Bm, xz, Alog, Dpar, hin, yg);

  {
    const int gx = D_MODEL/128, gy = NROWS/128;     // 8 x 64 = 512 blocks
    gemm_db2<2><<<gx*gy, 256, 0, stream>>>(
        yg, Woutt, nullptr, x, d_out, NROWS, D_MODEL, D_INNER, gx, gy);
  }

  (void)in_sizes; (void)n_in; (void)out_size; (void)ws_size;
}

// Round 8
// 626.944 us; speedup vs baseline: 1.5541x; 1.1114x over previous
//
#include <hip/hip_runtime.h>

typedef unsigned short u16;
typedef unsigned int   u32;

#define D_MODEL 1024
#define D_INNER 2048
#define D_STATE 16
#define SEQLEN  2048
#define BATCH   4
#define NROWS   (BATCH*SEQLEN)   // 8192
#define CHUNK   128
#define NCHUNK  (SEQLEN/CHUNK)   // 16

__device__ __forceinline__ float b2f(u16 v){
  union { u32 i; float f; } u; u.i = ((u32)v) << 16; return u.f;
}
__device__ __forceinline__ u16 f2b(float f){
  union { float f; u32 i; } u; u.f = f;
  u32 x = u.i;
  return (u16)((x + 0x7fffu + ((x >> 16) & 1u)) >> 16);  // RNE
}
__device__ __forceinline__ float h2f(u16 v){
  _Float16 h; __builtin_memcpy(&h, &v, 2); return (float)h;
}
__device__ __forceinline__ u16 f2h(float f){
  _Float16 h = (_Float16)f; u16 v; __builtin_memcpy(&v, &h, 2); return v;
}

typedef __bf16 bf16x8 __attribute__((ext_vector_type(8)));
typedef float  f32x4  __attribute__((ext_vector_type(4)));

// async global->LDS, 16B per lane; data for lane i lands at lds + i*16B.
__device__ __forceinline__ void async16(u16* lds, const u16* g){
  __builtin_amdgcn_global_load_lds(
      (const __attribute__((address_space(1))) void*)g,
      (__attribute__((address_space(3))) void*)lds,
      16, 0, 0);
}

__device__ __forceinline__ bf16x8 ldrow(const u16* p, bool ok){
  if (ok) return *reinterpret_cast<const bf16x8*>(p);
  u32 zi[4] = {0,0,0,0};
  bf16x8 z; __builtin_memcpy(&z, zi, 16); return z;
}

// ---------------------------------------------------------------------------
// fp32 [Kd][Nd] -> bf16 transposed [Nd][Kd]   (32x32 LDS tiles)
// ---------------------------------------------------------------------------
__global__ __launch_bounds__(256) void wcvt_t_kernel(
    const float* __restrict__ W, u16* __restrict__ Bt, int Kd, int Nd)
{
  __shared__ u16 tile[32][33];
  const int n0 = blockIdx.x*32, k0 = blockIdx.y*32;
  const int tx = threadIdx.x & 31, ty = threadIdx.x >> 5;  // ty 0..7
  #pragma unroll
  for (int i=0;i<32;i+=8)
    tile[ty+i][tx] = f2b(W[(size_t)(k0+ty+i)*Nd + n0+tx]);   // tile[k][n]
  __syncthreads();
  #pragma unroll
  for (int i=0;i<32;i+=8)
    Bt[(size_t)(n0+ty+i)*Kd + k0+tx] = tile[tx][ty+i];
}

// Wx [2048][32] cols 16..31 -> Wxt bf16 [16][2048]
__global__ __launch_bounds__(256) void wxcvt_kernel(
    const float* __restrict__ Wx, u16* __restrict__ Wxt)
{
  const int k = blockIdx.x*256 + threadIdx.x;   // 0..2047
  #pragma unroll
  for (int n=0;n<16;n++)
    Wxt[n*D_INNER + k] = f2b(Wx[(size_t)k*32 + 16 + n]);
}

// ---------------------------------------------------------------------------
// Fused LayerNorm: x[row][1024] fp32 -> xn bf16
// ---------------------------------------------------------------------------
__global__ __launch_bounds__(256) void ln_kernel(
    const float* __restrict__ x, const float* __restrict__ g,
    const float* __restrict__ be, u16* __restrict__ xn)
{
  const int row = blockIdx.x;
  const float* xr = x + (size_t)row * D_MODEL;
  const int tid = threadIdx.x;
  float v[4]; float s = 0.f, s2 = 0.f;
  #pragma unroll
  for (int j=0;j<4;j++){
    float f = xr[tid + 256*j];
    v[j] = f; s += f; s2 += f*f;
  }
  #pragma unroll
  for (int o=32;o>0;o>>=1){ s += __shfl_down(s,o); s2 += __shfl_down(s2,o); }
  __shared__ float sh[8];
  const int wave = tid>>6, lane = tid&63;
  if (lane==0){ sh[wave]=s; sh[4+wave]=s2; }
  __syncthreads();
  const float ts  = sh[0]+sh[1]+sh[2]+sh[3];
  const float ts2 = sh[4]+sh[5]+sh[6]+sh[7];
  const float mu  = ts * (1.f/D_MODEL);
  const float var = ts2 * (1.f/D_MODEL) - mu*mu;
  const float rstd = rsqrtf(var + 1e-5f);
  u16* xo = xn + (size_t)row * D_MODEL;
  #pragma unroll
  for (int j=0;j<4;j++){
    int i = tid + 256*j;
    xo[i] = f2b((v[j]-mu)*rstd * g[i] + be[i]);
  }
}

// ---------------------------------------------------------------------------
// 128x128 MFMA GEMM, BK=32, double-buffered single-barrier loop (R6, kept
// unchanged: established operating point, MfmaUtil ~21%, ~3 blocks/CU).
// ---------------------------------------------------------------------------
template<int EPI>
__global__ __launch_bounds__(256, 4) void gemm_db2(
    const u16* __restrict__ A, const u16* __restrict__ Bt,
    const float* __restrict__ bias, const float* __restrict__ resid,
    void* __restrict__ outv, int M, int N, int K, int gx, int gy)
{
  __shared__ __align__(16) u16 As[2*128*32];   // 16 KB (2 bufs x 8 KB)
  __shared__ __align__(16) u16 Bs[2*128*32];   // 16 KB
  const int tid  = threadIdx.x;
  const int wave = tid >> 6, lane = tid & 63;
  const int quad = lane >> 4, l16 = lane & 15;

  // XCD swizzle: consecutive blocks on one XCD share the same n-column.
  const int lid = blockIdx.x;
  const int xcd = lid & 7, q = lid >> 3;
  const int cpx = gx >> 3;
  const int qd  = q / gy;
  const int bx  = xcd*cpx + qd;
  const int by  = q - qd*gy;
  const int m0 = by*128, n0 = bx*128;
  const int wm = (wave & 1)*64, wn = (wave >> 1)*64;

  // staging: wave covers rows wave*32..+31 of both tiles
  const int srow = wave*32 + (lane >> 2);
  const int gcol = ((lane & 3) ^ ((lane >> 3) & 3)) * 8;  // swizzled granule
  const u16* pA = A  + (size_t)(m0 + srow)*K + gcol;
  const u16* pB = Bt + (size_t)(n0 + srow)*K + gcol;
  u16* lA = &As[wave*1024];   // + buf*4096 elems; +512 for rows +16
  u16* lB = &Bs[wave*1024];

  // fragment LDS byte offsets (within one buffer)
  const int sw   = quad ^ ((l16 >> 1) & 3);
  const int aoff = (wm + l16)*64 + sw*16;   // + mf*1024
  const int boff = (wn + l16)*64 + sw*16;   // + nf*1024

  f32x4 acc[4][4];
  #pragma unroll
  for (int i=0;i<4;i++)
    #pragma unroll
    for (int j=0;j<4;j++) acc[i][j] = (f32x4){0.f,0.f,0.f,0.f};

  // ---- prologue: stage tile 0 into buf 0 ----
  async16(lA,       pA);
  async16(lA + 512, pA + (size_t)16*K);
  async16(lB,       pB);
  async16(lB + 512, pB + (size_t)16*K);
  __syncthreads();                     // drains staging

  int cur = 0;
  #pragma unroll 1
  for (int k0 = 0; k0 < K; k0 += 32) {
    // ---- issue next tile's staging into the dead buffer FIRST ----
    const int kn = (k0 + 32 < K) ? k0 + 32 : k0;   // clamped tail (dead buf)
    const int nb = cur ^ 1;
    async16(lA + nb*4096,       pA + kn);
    async16(lA + nb*4096 + 512, pA + (size_t)16*K + kn);
    async16(lB + nb*4096,       pB + kn);
    async16(lB + nb*4096 + 512, pB + (size_t)16*K + kn);

    // ---- compute current buffer ----
    const char* aT = (const char*)As + cur*8192;
    const char* bT = (const char*)Bs + cur*8192;
    bf16x8 bfr[4];
    #pragma unroll
    for (int nf=0; nf<4; nf++)
      bfr[nf] = *reinterpret_cast<const bf16x8*>(bT + boff + nf*1024);
    #pragma unroll
    for (int mf=0; mf<4; mf++){
      bf16x8 af = *reinterpret_cast<const bf16x8*>(aT + aoff + mf*1024);
      #pragma unroll
      for (int nf=0; nf<4; nf++)
        acc[mf][nf] = __builtin_amdgcn_mfma_f32_16x16x32_bf16(af, bfr[nf], acc[mf][nf], 0, 0, 0);
    }

    __syncthreads();   // single sync point: drains prefetch + publishes
    cur = nb;
  }

  // ---- epilogue ----
  #pragma unroll
  for (int mf=0; mf<4; mf++){
    #pragma unroll
    for (int nf=0; nf<4; nf++){
      const int col = n0 + wn + nf*16 + l16;
      #pragma unroll
      for (int j=0;j<4;j++){
        const int row = m0 + wm + mf*16 + quad*4 + j;
        float v = acc[mf][nf][j];
        if (EPI == 1) {
          v += bias[col];
          v = (v > 20.f) ? v : log1pf(__expf(v));
          ((u16*)outv)[(size_t)row*N + col] = f2h(v);       // delta fp16
        } else if (EPI == 2) {
          v += resid[(size_t)row*N + col];
          ((float*)outv)[(size_t)row*N + col] = v;          // final out fp32
        } else {
          ((u16*)outv)[(size_t)row*N + col] = f2b(v);       // bf16 activation
        }
      }
    }
  }
}

// ---------------------------------------------------------------------------
// FUSED: causal depthwise conv(4) + bias + SiLU -> u (bf16) AND x_proj
// B-columns: Bm[bt][n] = sum_c u[c]*Wxt[n][c].
// R8 rework of the R7 latency-bound version (148 us, HBM 8.6%, VALU 18%):
//  * 8 rows per block, sliding conv window: xz row loaded ONCE (11 loads
//    per 8 outputs vs 32), conv weights/bias hoisted to registers,
//    Wxt re-reads become L1 hits across rows; grid 8192 -> 1024 blocks.
//  * value-splitting butterfly: 16 values over 64 lanes in 17 shfls
//    (vs 96): split responsibility per level; after off=4 each lane
//    holds one value n=(lane>>2)&15 partial over 16 lanes; off=2,1
//    merge the 4 disjoint partials.  All register indices compile-time.
// ---------------------------------------------------------------------------
__global__ __launch_bounds__(256) void conv_silu_xproj_kernel(
    const u16* __restrict__ xz, const float* __restrict__ cw,
    const float* __restrict__ cb, const u16* __restrict__ Wxt,
    u16* __restrict__ u, float* __restrict__ Bm)
{
  const int bt0 = blockIdx.x * 8;       // 8 consecutive rows, same sequence
  const int t0  = bt0 & (SEQLEN-1);
  const int c0  = threadIdx.x * 8;
  const int wave = threadIdx.x >> 6, lane = threadIdx.x & 63;
  const u16* xb = xz + c0;

  // hoisted conv weights/bias (static indices -> registers)
  float cwv0[8], cwv1[8], cwv2[8], cwv3[8], cbv[8];
  #pragma unroll
  for (int j=0;j<8;j++){
    cwv0[j] = cw[(c0+j)*4 + 0];
    cwv1[j] = cw[(c0+j)*4 + 1];
    cwv2[j] = cw[(c0+j)*4 + 2];
    cwv3[j] = cw[(c0+j)*4 + 3];
    cbv[j]  = cb[c0+j];
  }

  // sliding window: xw0..xw2 = rows t-3..t-1 (zeros before seq start)
  bf16x8 xw0 = ldrow(xb + (long long)(bt0-3)*4096, t0 >= 3);
  bf16x8 xw1 = ldrow(xb + (long long)(bt0-2)*4096, t0 >= 2);
  bf16x8 xw2 = ldrow(xb + (long long)(bt0-1)*4096, t0 >= 1);

  __shared__ float red[4][16];

  #pragma unroll
  for (int r=0; r<8; ++r){
    const int bt = bt0 + r;
    bf16x8 xw3 = *reinterpret_cast<const bf16x8*>(xb + (size_t)bt*4096);

    float sv[8]; u16 o[8];
    #pragma unroll
    for (int j=0;j<8;j++){
      float a = cbv[j];
      a = fmaf(cwv0[j], (float)xw0[j], a);
      a = fmaf(cwv1[j], (float)xw1[j], a);
      a = fmaf(cwv2[j], (float)xw2[j], a);
      a = fmaf(cwv3[j], (float)xw3[j], a);
      sv[j] = a / (1.f + __expf(-a));
      o[j] = f2b(sv[j]);
    }
    __builtin_memcpy(u + (size_t)bt*D_INNER + c0, o, 16);

    // x_proj partials over this thread's 8 channels
    float pn[16];
    #pragma unroll
    for (int n=0;n<16;n++){
      bf16x8 wv = *reinterpret_cast<const bf16x8*>(Wxt + (size_t)n*D_INNER + c0);
      float s = 0.f;
      #pragma unroll
      for (int j=0;j<8;j++) s = fmaf(sv[j], (float)wv[j], s);
      pn[n] = s;
    }

    // value-splitting butterfly: 17 shfls for 16 sums over 64 lanes
    float r8v[8];
    #pragma unroll
    for (int n=0;n<8;n++){
      float a = (lane < 32) ? pn[n]   : pn[n+8];
      float b = (lane < 32) ? pn[n+8] : pn[n];
      r8v[n] = a + __shfl_xor(b, 32);
    }
    float r4v[4];
    #pragma unroll
    for (int n=0;n<4;n++){
      float a = ((lane & 16)==0) ? r8v[n]   : r8v[n+4];
      float b = ((lane & 16)==0) ? r8v[n+4] : r8v[n];
      r4v[n] = a + __shfl_xor(b, 16);
    }
    float r2v[2];
    #pragma unroll
    for (int n=0;n<2;n++){
      float a = ((lane & 8)==0) ? r2v[0]*0.f + r4v[n] : r4v[n+2];
      float b = ((lane & 8)==0) ? r4v[n+2] : r4v[n];
      r2v[n] = a + __shfl_xor(b, 8);
    }
    float a1 = ((lane & 4)==0) ? r2v[0] : r2v[1];
    float b1 = ((lane & 4)==0) ? r2v[1] : r2v[0];
    float rv = a1 + __shfl_xor(b1, 4);
    rv += __shfl_xor(rv, 2);
    rv += __shfl_xor(rv, 1);   // full wave sum for n=(lane>>2)&15

    if ((lane & 3) == 0) red[wave][(lane>>2)&15] = rv;
    __syncthreads();
    if (threadIdx.x < 16){
      const int n = threadIdx.x;
      Bm[(size_t)bt*16 + n] = red[0][n]+red[1][n]+red[2][n]+red[3][n];
    }
    __syncthreads();

    xw0 = xw1; xw1 = xw2; xw2 = xw3;
  }
}

// ---------------------------------------------------------------------------
// Chunked selective scan, 3 passes (exact linear-recurrence decomposition).
// ---------------------------------------------------------------------------
__global__ __launch_bounds__(256) void scan_partial(
    const u16* __restrict__ uu, const u16* __restrict__ delta16,
    const float* __restrict__ Bm, const float* __restrict__ Alog,
    float* __restrict__ hend, float* __restrict__ sumdt)
{
  const int b = blockIdx.y, ch = blockIdx.z;
  const int c = blockIdx.x*256 + threadIdx.x;
  const int row0 = b*SEQLEN + ch*CHUNK;
  float A[16], h[16];
  #pragma unroll
  for (int s=0;s<16;s++){ A[s] = -__expf(Alog[c*16+s]); h[s]=0.f; }
  __shared__ float Bsh[CHUNK*16];
  const float* src = Bm + (size_t)row0*16;
  #pragma unroll
  for (int j=0;j<8;j++) Bsh[threadIdx.x + 256*j] = src[threadIdx.x + 256*j];
  __syncthreads();

  float S = 0.f;
  float dta[8], uva[8], dtb[8], uvb[8];
  #pragma unroll
  for (int j=0;j<8;j++){
    size_t r = (size_t)(row0+j);
    dta[j] = h2f(delta16[r*D_INNER+c]);
    uva[j] = b2f(uu[r*D_INNER+c]);
  }
  #pragma unroll 1
  for (int g=0; g<CHUNK; g+=16){
    #pragma unroll
    for (int j=0;j<8;j++){
      int tl = g+8+j; tl = tl < CHUNK ? tl : CHUNK-1;
      size_t r = (size_t)(row0+tl);
      dtb[j] = h2f(delta16[r*D_INNER+c]);
      uvb[j] = b2f(uu[r*D_INNER+c]);
    }
    #pragma unroll
    for (int j=0;j<8;j++){
      float dt=dta[j], uv=uva[j]; S += dt; float xv=dt*uv;
      const float* Bt = &Bsh[(g+j)*16];
      #pragma unroll
      for (int s=0;s<16;s++) h[s] = fmaf(h[s], __expf(dt*A[s]), xv*Bt[s]);
    }
    #pragma unroll
    for (int j=0;j<8;j++){
      int tl = g+16+j; tl = tl < CHUNK ? tl : CHUNK-1;
      size_t r = (size_t)(row0+tl);
      dta[j] = h2f(delta16[r*D_INNER+c]);
      uva[j] = b2f(uu[r*D_INNER+c]);
    }
    #pragma unroll
    for (int j=0;j<8;j++){
      float dt=dtb[j], uv=uvb[j]; S += dt; float xv=dt*uv;
      const float* Bt = &Bsh[(g+8+j)*16];
      #pragma unroll
      for (int s=0;s<16;s++) h[s] = fmaf(h[s], __expf(dt*A[s]), xv*Bt[s]);
    }
  }
  const size_t base = ((size_t)(b*NCHUNK+ch)*16)*D_INNER + c;
  #pragma unroll
  for (int s=0;s<16;s++) hend[base + (size_t)s*D_INNER] = h[s];
  sumdt[(size_t)(b*NCHUNK+ch)*D_INNER + c] = S;
}

// Parallelized over (channel, state).
__global__ __launch_bounds__(256) void scan_combine(
    const float* __restrict__ hend, const float* __restrict__ sumdt,
    const float* __restrict__ Alog, float* __restrict__ hin)
{
  const int b = blockIdx.y;
  const int idx = blockIdx.x*256 + threadIdx.x;   // 0..D_INNER*16-1
  const int s = idx >> 11, c = idx & (D_INNER-1);
  const float A = -__expf(Alog[c*16+s]);
  float h = 0.f;
  #pragma unroll 1
  for (int k=0;k<NCHUNK;k++){
    const size_t base = (((size_t)(b*NCHUNK+k)*16)+s)*D_INNER + c;
    hin[base] = h;
    const float S = sumdt[(size_t)(b*NCHUNK+k)*D_INNER + c];
    h = fmaf(h, __expf(S*A), hend[base]);
  }
}

__global__ __launch_bounds__(256) void scan_final(
    const u16* __restrict__ uu, const u16* __restrict__ delta16,
    const float* __restrict__ Bm, const u16* __restrict__ xz,
    const float* __restrict__ Alog, const float* __restrict__ Dpar,
    const float* __restrict__ hin, u16* __restrict__ yg)
{
  const int b = blockIdx.y, ch = blockIdx.z;
  const int c = blockIdx.x*256 + threadIdx.x;
  const int row0 = b*SEQLEN + ch*CHUNK;
  float A[16], h[16];
  const size_t base = ((size_t)(b*NCHUNK+ch)*16)*D_INNER + c;
  #pragma unroll
  for (int s=0;s<16;s++){
    A[s] = -__expf(Alog[c*16+s]);
    h[s] = hin[base + (size_t)s*D_INNER];
  }
  const float Dc = Dpar[c];
  __shared__ float Bsh[CHUNK*16];
  const float* src = Bm + (size_t)row0*16;
  #pragma unroll
  for (int j=0;j<8;j++) Bsh[threadIdx.x + 256*j] = src[threadIdx.x + 256*j];
  __syncthreads();

  float dta[8], uva[8], zva[8], dtb[8], uvb[8], zvb[8];
  #pragma unroll
  for (int j=0;j<8;j++){
    size_t r = (size_t)(row0+j);
    dta[j] = h2f(delta16[r*D_INNER+c]);
    uva[j] = b2f(uu[r*D_INNER+c]);
    zva[j] = b2f(xz[r*4096 + D_INNER + c]);
  }
  #pragma unroll 1
  for (int g=0; g<CHUNK; g+=16){
    #pragma unroll
    for (int j=0;j<8;j++){
      int tl = g+8+j; tl = tl < CHUNK ? tl : CHUNK-1;
      size_t r = (size_t)(row0+tl);
      dtb[j] = h2f(delta16[r*D_INNER+c]);
      uvb[j] = b2f(uu[r*D_INNER+c]);
      zvb[j] = b2f(xz[r*4096 + D_INNER + c]);
    }
    #pragma unroll
    for (int j=0;j<8;j++){
      float dt=dta[j], uv=uva[j], zv=zva[j];
      float xv=dt*uv, y=0.f;
      const float* Bt = &Bsh[(g+j)*16];
      #pragma unroll
      for (int s=0;s<16;s++){
        h[s] = fmaf(h[s], __expf(dt*A[s]), xv*Bt[s]);
        y += h[s];
      }
      y = fmaf(uv, Dc, y);
      float gz = zv/(1.f+__expf(-zv));
      yg[(size_t)(row0+g+j)*D_INNER + c] = f2b(y*gz);
    }
    #pragma unroll
    for (int j=0;j<8;j++){
      int tl = g+16+j; tl = tl < CHUNK ? tl : CHUNK-1;
      size_t r = (size_t)(row0+tl);
      dta[j] = h2f(delta16[r*D_INNER+c]);
      uva[j] = b2f(uu[r*D_INNER+c]);
      zva[j] = b2f(xz[r*4096 + D_INNER + c]);
    }
    #pragma unroll
    for (int j=0;j<8;j++){
      float dt=dtb[j], uv=uvb[j], zv=zvb[j];
      float xv=dt*uv, y=0.f;
      const float* Bt = &Bsh[(g+8+j)*16];
      #pragma unroll
      for (int s=0;s<16;s++){
        h[s] = fmaf(h[s], __expf(dt*A[s]), xv*Bt[s]);
        y += h[s];
      }
      y = fmaf(uv, Dc, y);
      float gz = zv/(1.f+__expf(-zv));
      yg[(size_t)(row0+g+8+j)*D_INNER + c] = f2b(y*gz);
    }
  }
}

// ---------------------------------------------------------------------------
extern "C" void kernel_launch(void* const* d_in, const int* in_sizes, int n_in,
                              void* d_out, int out_size, void* d_ws, size_t ws_size,
                              hipStream_t stream)
{
  const float* x    = (const float*)d_in[0];
  const float* lng  = (const float*)d_in[1];
  const float* lnb  = (const float*)d_in[2];
  const float* W1   = (const float*)d_in[3];
  const float* cw   = (const float*)d_in[4];
  const float* cb   = (const float*)d_in[5];
  const float* Wx   = (const float*)d_in[6];
  const float* Wdt  = (const float*)d_in[7];
  const float* dtb  = (const float*)d_in[8];
  const float* Alog = (const float*)d_in[9];
  const float* Dpar = (const float*)d_in[10];
  const float* Wout = (const float*)d_in[11];

  // workspace layout (MiB offsets), total ~199 MiB
  char* ws = (char*)d_ws;
  u16*   dlt   = (u16*)(ws);
  u16*   xn    = (u16*)(ws);                 // alias (sequenced)
  u16*   xz    = (u16*)(ws + (32llu<<20));
  u16*   uu    = (u16*)(ws + (96llu<<20));
  float* Bm    = (float*)(ws + (128llu<<20));
  u16*   W1t   = (u16*)(ws + (129llu<<20));
  u16*   Wdtt  = (u16*)(ws + (137llu<<20));
  u16*   Woutt = (u16*)(ws + (145llu<<20));
  u16*   yg    = (u16*)(ws + (149llu<<20));
  float* hend  = (float*)(ws + (181llu<<20));
  float* sumdt = (float*)(ws + (189llu<<20));
  float* hin   = (float*)(ws + (190llu<<20));
  u16*   Wxt   = (u16*)(ws + (198llu<<20));

  // weights -> bf16, transposed to [N][K]
  wcvt_t_kernel<<<dim3(2*D_INNER/32, D_MODEL/32), 256, 0, stream>>>(W1,  W1t,  D_MODEL, 2*D_INNER);
  wcvt_t_kernel<<<dim3(D_INNER/32,  D_INNER/32), 256, 0, stream>>>(Wdt, Wdtt, D_INNER, D_INNER);
  wcvt_t_kernel<<<dim3(D_MODEL/32,  D_INNER/32), 256, 0, stream>>>(Wout,Woutt,D_INNER, D_MODEL);
  wxcvt_kernel<<<D_INNER/256, 256, 0, stream>>>(Wx, Wxt);

  ln_kernel<<<NROWS, 256, 0, stream>>>(x, lng, lnb, xn);

  {
    const int gx = 2*D_INNER/128, gy = NROWS/128;   // 32 x 64 = 2048 blocks
    gemm_db2<0><<<gx*gy, 256, 0, stream>>>(
        xn, W1t, nullptr, nullptr, (void*)xz, NROWS, 2*D_INNER, D_MODEL, gx, gy);
  }

  conv_silu_xproj_kernel<<<NROWS/8, 256, 0, stream>>>(xz, cw, cb, Wxt, uu, Bm);

  {
    const int gx = D_INNER/128, gy = NROWS/128;     // 16 x 64 = 1024 blocks
    gemm_db2<1><<<gx*gy, 256, 0, stream>>>(
        uu, Wdtt, dtb, nullptr, (void*)dlt, NROWS, D_INNER, D_INNER, gx, gy);
  }

  scan_partial<<<dim3(D_INNER/256, BATCH, NCHUNK), 256, 0, stream>>>(
      uu, dlt, Bm, Alog, hend, sumdt);
  scan_combine<<<dim3(D_INNER*16/256, BATCH), 256, 0, stream>>>(
      hend, sumdt, Alog, hin);
  scan_final<<<dim3(D_INNER/256, BATCH, NCHUNK), 256, 0, stream>>>(
      uu, dlt, Bm, xz, Alog, Dpar, hin, yg);

  {
    const int gx = D_MODEL/128, gy = NROWS/128;     // 8 x 64 = 512 blocks
    gemm_db2<2><<<gx*gy, 256, 0, stream>>>(
        yg, Woutt, nullptr, x, d_out, NROWS, D_MODEL, D_INNER, gx, gy);
  }

  (void)in_sizes; (void)n_in; (void)out_size; (void)ws_size;
}